// Round 1
// baseline (1236.858 us; speedup 1.0000x reference)
//
#include <hip/hip_runtime.h>
#include <hip/hip_bf16.h>

#define B_    64
#define T_    256
#define K_    256
#define L_    51
#define LL_   2601   // L*L
#define NPAD_ 2624   // 41*64, padded N for the GEMM

typedef __bf16 bf16x8 __attribute__((ext_vector_type(8)));
typedef float  f32x4  __attribute__((ext_vector_type(4)));
typedef unsigned int u32x4 __attribute__((ext_vector_type(4)));

static __device__ __forceinline__ bf16x8 as_bf16x8(u32x4 u) {
    return __builtin_bit_cast(bf16x8, u);
}

// ---------------------------------------------------------------------------
// Prep: fused transposed weight W't[n][k] = trans_W[k][n] + state_W[k][n%L]
//       (bf16, zero-padded to NPAD_ rows), bias'[n] = trans_b[n]+state_b[n%L]
// blockIdx.x = k (256 blocks); threads stride over n (coalesced trans_W read)
// ---------------------------------------------------------------------------
__global__ void prep_w(const float* __restrict__ trans_W, const float* __restrict__ trans_b,
                       const float* __restrict__ state_W, const float* __restrict__ state_b,
                       __hip_bfloat16* __restrict__ Wt, float* __restrict__ bias)
{
    const int k = blockIdx.x;  // 0..255
    for (int n = threadIdx.x; n < NPAD_; n += blockDim.x) {
        float w = 0.f;
        if (n < LL_) {
            int j = n % L_;
            w = trans_W[(size_t)k * LL_ + n] + state_W[k * L_ + j];
        }
        Wt[(size_t)n * K_ + k] = __float2bfloat16(w);
        if (k == 0) {
            float bv = 0.f;
            if (n < LL_) bv = trans_b[n] + state_b[n % L_];
            bias[n] = bv;
        }
    }
}

// x fp32 -> bf16
__global__ void prep_x(const float* __restrict__ x, __hip_bfloat16* __restrict__ xb, int ntot)
{
    for (int idx = blockIdx.x * blockDim.x + threadIdx.x; idx < ntot;
         idx += gridDim.x * blockDim.x)
        xb[idx] = __float2bfloat16(x[idx]);
}

// ---------------------------------------------------------------------------
// GEMM: energies e[m][n] = (x[m]·W'[:,n] + b'[n]) * mask(m), m = b*Tc + tl,
// token t = t0 + tl. MFMA 16x16x32 bf16. Per wave: 16 rows x 64 cols (4 frags
// share one A frag). Block = 4 waves = 64 rows. Grid = (41, Tc).
// ---------------------------------------------------------------------------
__global__ __launch_bounds__(256) void gemm_energy(
    const __hip_bfloat16* __restrict__ xb,   // [B*T][K]
    const __hip_bfloat16* __restrict__ Wt,   // [NPAD][K]
    const float* __restrict__ bias,          // [NPAD]
    const float* __restrict__ mask,          // [B][T]
    __hip_bfloat16* __restrict__ eout,       // [B*Tc][LL]
    int t0, int Tc, int TcShift)
{
    const int lane = threadIdx.x & 63;
    const int wave = threadIdx.x >> 6;
    const int quad = lane >> 4;
    const int l16  = lane & 15;
    const int m0 = (blockIdx.y * 4 + wave) * 16;
    const int n0 = blockIdx.x * 64;

    // A-operand row for this lane: m = m0 + (lane&15), elems k = quad*8 + j
    const int am  = m0 + l16;
    const int ab  = am >> TcShift;
    const int atl = am & (Tc - 1);
    const u32x4* ap = reinterpret_cast<const u32x4*>(xb + (size_t)(ab * T_ + t0 + atl) * K_);

    const u32x4* bp[4];
#pragma unroll
    for (int f = 0; f < 4; ++f)
        bp[f] = reinterpret_cast<const u32x4*>(Wt + (size_t)(n0 + f * 16 + l16) * K_);

    f32x4 acc[4] = {};
#pragma unroll
    for (int kk = 0; kk < 8; ++kk) {               // K = 8 * 32
        bf16x8 a = as_bf16x8(ap[kk * 4 + quad]);
#pragma unroll
        for (int f = 0; f < 4; ++f) {
            bf16x8 bfr = as_bf16x8(bp[f][kk * 4 + quad]);
            acc[f] = __builtin_amdgcn_mfma_f32_16x16x32_bf16(a, bfr, acc[f], 0, 0, 0);
        }
    }

    // Epilogue: C/D layout col = lane&15, row = quad*4 + r
#pragma unroll
    for (int r = 0; r < 4; ++r) {
        const int m  = m0 + quad * 4 + r;
        const int b  = m >> TcShift;
        const int tl = m & (Tc - 1);
        const float mval = mask[b * T_ + t0 + tl];
#pragma unroll
        for (int f = 0; f < 4; ++f) {
            const int n = n0 + f * 16 + l16;
            if (n < LL_) {
                float v = (acc[f][r] + bias[n]) * mval;
                eout[(size_t)m * LL_ + n] = __float2bfloat16(v);
            }
        }
    }
}

// ---------------------------------------------------------------------------
// Forward-algorithm scan over one chunk of T. One block per batch element.
// 4 waves split the i (previous label) range for the per-j logsumexp.
// State (partition, tgt energy, prev label) persists in ws across chunks.
// ---------------------------------------------------------------------------
__global__ __launch_bounds__(256) void scan_kernel(
    const __hip_bfloat16* __restrict__ e,    // [B*Tc][LL]
    const float* __restrict__ mask,          // [B][T]
    const int* __restrict__ target,          // [B][T]
    float* __restrict__ part_ws,             // [B][L]
    float* __restrict__ tgt_ws,              // [B]
    int* __restrict__ prev_ws,               // [B]
    float* __restrict__ out,                 // [B]
    int t0, int Tc)
{
    __shared__ float e_lds[LL_];
    __shared__ float part_lds[L_];
    __shared__ float pm_lds[4][64];
    __shared__ float ps_lds[4][64];
    __shared__ float tgt_e_s;
    __shared__ int   prev_s;

    const int b    = blockIdx.x;
    const int tid  = threadIdx.x;
    const int wave = tid >> 6;
    const int lane = tid & 63;
    const int i_begin = wave * 13;     // waves cover i-ranges 13/13/13/12

    if (t0 > 0) {
        if (tid < L_) part_lds[tid] = part_ws[b * L_ + tid];
        if (tid == 0) { tgt_e_s = tgt_ws[b]; prev_s = prev_ws[b]; }
    }

    for (int tl = 0; tl < Tc; ++tl) {
        const int t = t0 + tl;
        __syncthreads();   // prior iter done with e_lds; part updates visible
        const __hip_bfloat16* erow = e + (size_t)(b * Tc + tl) * LL_;
        for (int idx = tid; idx < LL_; idx += 256)
            e_lds[idx] = __bfloat162float(erow[idx]);
        __syncthreads();   // e_lds ready

        if (t == 0) {
            if (wave == 0) {
                if (lane < L_) part_lds[lane] = e_lds[(L_ - 1) * L_ + lane];
                if (lane == 0) {
                    int tg = target[b * T_];
                    tgt_e_s = e_lds[(L_ - 1) * L_ + tg];
                    prev_s  = tg;
                }
            }
        } else {
            const int j = lane;
            if (j < L_) {
                float vv[13];
                float pm = -1e30f;
#pragma unroll
                for (int c = 0; c < 13; ++c) {
                    const int i  = i_begin + c;
                    const int ii = (i < L_) ? i : 0;
                    float v = (i < L_) ? (e_lds[ii * L_ + j] + part_lds[ii]) : -1e30f;
                    vv[c] = v;
                    pm = fmaxf(pm, v);
                }
                float ps = 0.f;
#pragma unroll
                for (int c = 0; c < 13; ++c) ps += __expf(vv[c] - pm);
                pm_lds[wave][j] = pm;
                ps_lds[wave][j] = ps;
            }
            __syncthreads();   // partials ready; all part_lds reads done
            if (wave == 0 && j < L_) {
                float M = pm_lds[0][j];
#pragma unroll
                for (int w = 1; w < 4; ++w) M = fmaxf(M, pm_lds[w][j]);
                float S = 0.f;
#pragma unroll
                for (int w = 0; w < 4; ++w) S += ps_lds[w][j] * __expf(pm_lds[w][j] - M);
                const float pn   = M + __logf(S);
                const float po   = part_lds[j];
                const float mval = mask[b * T_ + t];
                part_lds[j] = po + (pn - po) * mval;
            }
            if (tid == 0) {
                int tg = target[b * T_ + t];
                tgt_e_s += e_lds[prev_s * L_ + tg];
                prev_s = tg;
            }
        }
    }
    __syncthreads();

    if (tid < L_) part_ws[b * L_ + tid] = part_lds[tid];
    if (tid == 0) {
        tgt_ws[b]  = tgt_e_s;
        prev_ws[b] = prev_s;
        if (t0 + Tc == T_) {   // final chunk: emit loss
            float M = part_lds[0];
            for (int jj = 1; jj < L_; ++jj) M = fmaxf(M, part_lds[jj]);
            float S = 0.f;
            for (int jj = 0; jj < L_; ++jj) S += __expf(part_lds[jj] - M);
            out[b] = M + __logf(S) - tgt_e_s;
        }
    }
}

// ---------------------------------------------------------------------------
extern "C" void kernel_launch(void* const* d_in, const int* in_sizes, int n_in,
                              void* d_out, int out_size, void* d_ws, size_t ws_size,
                              hipStream_t stream)
{
    (void)in_sizes; (void)n_in; (void)out_size;
    const float* x       = (const float*)d_in[0];
    const float* mask    = (const float*)d_in[1];
    const int*   target  = (const int*)d_in[2];
    const float* state_W = (const float*)d_in[3];
    const float* state_b = (const float*)d_in[4];
    const float* trans_W = (const float*)d_in[5];
    const float* trans_b = (const float*)d_in[6];
    float* out = (float*)d_out;

    char* ws = (char*)d_ws;
    size_t off = 0;
    auto alloc = [&](size_t bytes) -> void* {
        void* p = ws + off;
        off = (off + bytes + 255) & ~(size_t)255;
        return p;
    };

    __hip_bfloat16* Wt   = (__hip_bfloat16*)alloc((size_t)NPAD_ * K_ * 2);
    float*          bias = (float*)alloc((size_t)NPAD_ * 4);
    __hip_bfloat16* xb   = (__hip_bfloat16*)alloc((size_t)B_ * T_ * K_ * 2);
    float*          part = (float*)alloc((size_t)B_ * L_ * 4);
    float*          tgte = (float*)alloc((size_t)B_ * 4);
    int*            prev = (int*)alloc((size_t)B_ * 4);
    const size_t fixed = off;

    // Chunk T so the energy buffer fits in ws (power-of-two Tc, min 4)
    int Tc = 256;
    while (Tc > 4 && fixed + (size_t)Tc * B_ * LL_ * 2 > ws_size) Tc >>= 1;
    __hip_bfloat16* echunk = (__hip_bfloat16*)alloc((size_t)Tc * B_ * LL_ * 2);
    int TcShift = 0;
    while ((1 << TcShift) < Tc) ++TcShift;

    prep_w<<<dim3(K_), 256, 0, stream>>>(trans_W, trans_b, state_W, state_b, Wt, bias);
    prep_x<<<dim3(4096), 256, 0, stream>>>(x, xb, B_ * T_ * K_);

    for (int t0 = 0; t0 < T_; t0 += Tc) {
        gemm_energy<<<dim3(NPAD_ / 64, Tc), 256, 0, stream>>>(
            xb, Wt, bias, mask, echunk, t0, Tc, TcShift);
        scan_kernel<<<dim3(B_), 256, 0, stream>>>(
            echunk, mask, target, part, tgte, prev, out, t0, Tc);
    }
}

// Round 2
// 569.856 us; speedup vs baseline: 2.1705x; 2.1705x over previous
//
#include <hip/hip_runtime.h>
#include <hip/hip_bf16.h>

#define B_    64
#define T_    256
#define K_    256
#define L_    51
#define LL_   2601   // L*L
#define NPAD_ 2624   // 41*64, padded N for the GEMM and energy-row stride

typedef __bf16 bf16x8 __attribute__((ext_vector_type(8)));
typedef float  f32x4  __attribute__((ext_vector_type(4)));
typedef unsigned int u32x4 __attribute__((ext_vector_type(4)));

static __device__ __forceinline__ bf16x8 as_bf16x8(u32x4 u) {
    return __builtin_bit_cast(bf16x8, u);
}

static __device__ __forceinline__ float b2f(unsigned short u) {
    union { unsigned int i; float f; } c;
    c.i = ((unsigned int)u) << 16;
    return c.f;
}

// ---------------------------------------------------------------------------
// Prep: fused transposed weight W't[n][k] = trans_W[k][n] + state_W[k][n%L]
//       (bf16, zero-padded to NPAD_ rows), bias'[n] = trans_b[n]+state_b[n%L]
// ---------------------------------------------------------------------------
__global__ void prep_w(const float* __restrict__ trans_W, const float* __restrict__ trans_b,
                       const float* __restrict__ state_W, const float* __restrict__ state_b,
                       __hip_bfloat16* __restrict__ Wt, float* __restrict__ bias)
{
    const int k = blockIdx.x;  // 0..255
    for (int n = threadIdx.x; n < NPAD_; n += blockDim.x) {
        float w = 0.f;
        if (n < LL_) {
            int j = n % L_;
            w = trans_W[(size_t)k * LL_ + n] + state_W[k * L_ + j];
        }
        Wt[(size_t)n * K_ + k] = __float2bfloat16(w);
        if (k == 0) {
            float bv = 0.f;
            if (n < LL_) bv = trans_b[n] + state_b[n % L_];
            bias[n] = bv;
        }
    }
}

// x fp32 -> bf16
__global__ void prep_x(const float* __restrict__ x, __hip_bfloat16* __restrict__ xb, int ntot)
{
    for (int idx = blockIdx.x * blockDim.x + threadIdx.x; idx < ntot;
         idx += gridDim.x * blockDim.x)
        xb[idx] = __float2bfloat16(x[idx]);
}

// ---------------------------------------------------------------------------
// GEMM: e[m][n] = (x[m]·W'[:,n] + b'[n]) * mask(m). Rows padded to NPAD_.
// MFMA 16x16x32 bf16; per wave 16 rows x 64 cols. Grid = (41, Tc).
// ---------------------------------------------------------------------------
__global__ __launch_bounds__(256) void gemm_energy(
    const __hip_bfloat16* __restrict__ xb,   // [B*T][K]
    const __hip_bfloat16* __restrict__ Wt,   // [NPAD][K]
    const float* __restrict__ bias,          // [NPAD]
    const float* __restrict__ mask,          // [B][T]
    __hip_bfloat16* __restrict__ eout,       // [B*Tc][NPAD]
    int t0, int Tc, int TcShift)
{
    const int lane = threadIdx.x & 63;
    const int wave = threadIdx.x >> 6;
    const int quad = lane >> 4;
    const int l16  = lane & 15;
    const int m0 = (blockIdx.y * 4 + wave) * 16;
    const int n0 = blockIdx.x * 64;

    const int am  = m0 + l16;
    const int ab  = am >> TcShift;
    const int atl = am & (Tc - 1);
    const u32x4* ap = reinterpret_cast<const u32x4*>(xb + (size_t)(ab * T_ + t0 + atl) * K_);

    const u32x4* bp[4];
#pragma unroll
    for (int f = 0; f < 4; ++f)
        bp[f] = reinterpret_cast<const u32x4*>(Wt + (size_t)(n0 + f * 16 + l16) * K_);

    f32x4 acc[4] = {};
#pragma unroll
    for (int kk = 0; kk < 8; ++kk) {               // K = 8 * 32
        bf16x8 a = as_bf16x8(ap[kk * 4 + quad]);
#pragma unroll
        for (int f = 0; f < 4; ++f) {
            bf16x8 bfr = as_bf16x8(bp[f][kk * 4 + quad]);
            acc[f] = __builtin_amdgcn_mfma_f32_16x16x32_bf16(a, bfr, acc[f], 0, 0, 0);
        }
    }

    // C/D layout: col = lane&15, row = quad*4 + r
#pragma unroll
    for (int r = 0; r < 4; ++r) {
        const int m  = m0 + quad * 4 + r;
        const int b  = m >> TcShift;
        const int tl = m & (Tc - 1);
        const float mval = mask[b * T_ + t0 + tl];
#pragma unroll
        for (int f = 0; f < 4; ++f) {
            const int n = n0 + f * 16 + l16;
            float v = (acc[f][r] + bias[n]) * mval;
            eout[(size_t)m * NPAD_ + n] = __float2bfloat16(v);
        }
    }
}

// ---------------------------------------------------------------------------
// Forward-algorithm scan: one block per batch element, double-buffered LDS
// energy tile (bf16) with register-staged prefetch of step t+1.
// ---------------------------------------------------------------------------
#define ROW16_ (NPAD_ / 8)          // 328 x 16B chunks per energy row
#define TAIL_  (ROW16_ - 256)       // 72 second-round chunks

__global__ __launch_bounds__(256) void scan_kernel(
    const __hip_bfloat16* __restrict__ e,    // [B*Tc][NPAD]
    const float* __restrict__ mask,          // [B][T]
    const int* __restrict__ target,          // [B][T]
    float* __restrict__ part_ws,             // [B][L]
    float* __restrict__ tgt_ws,              // [B]
    int* __restrict__ prev_ws,               // [B]
    float* __restrict__ out,                 // [B]
    int t0, int Tc)
{
    __shared__ u32x4 e_buf[2][ROW16_];       // 2 x 5248 B, raw bf16
    __shared__ float part_lds[L_];
    __shared__ float pm_lds[4][64];
    __shared__ float ps_lds[4][64];
    __shared__ float mask_lds[T_];
    __shared__ int   tgt_lds[T_];
    __shared__ float tgt_e_s;
    __shared__ int   prev_s;

    const int b    = blockIdx.x;
    const int tid  = threadIdx.x;
    const int wave = tid >> 6;
    const int lane = tid & 63;
    const int i_begin = wave * 13;           // waves cover i-ranges 13/13/13/12

    // One-time preload of per-chain mask / target rows (off the critical path)
    mask_lds[tid] = mask[b * T_ + tid];
    tgt_lds[tid]  = target[b * T_ + tid];

    if (t0 > 0) {
        if (tid < L_) part_lds[tid] = part_ws[b * L_ + tid];
        if (tid == 0) { tgt_e_s = tgt_ws[b]; prev_s = prev_ws[b]; }
    }

    // Prologue: stage tile 0 into registers
    const u32x4* gp = reinterpret_cast<const u32x4*>(e + (size_t)b * Tc * NPAD_);
    u32x4 r0 = gp[tid];
    u32x4 r1 = {};
    if (tid < TAIL_) r1 = gp[256 + tid];

    int buf = 0;
    for (int tl = 0; tl < Tc; ++tl) {
        const int t = t0 + tl;

        // Commit staged registers to this step's LDS buffer
        e_buf[buf][tid] = r0;
        if (tid < TAIL_) e_buf[buf][256 + tid] = r1;
        __syncthreads();                     // tile ready; prior part update visible

        // Prefetch step tl+1 (has the whole step to complete)
        if (tl + 1 < Tc) {
            const u32x4* gn = gp + (size_t)(tl + 1) * ROW16_;
            r0 = gn[tid];
            if (tid < TAIL_) r1 = gn[256 + tid];
        }

        const unsigned short* e16 = reinterpret_cast<const unsigned short*>(&e_buf[buf][0]);

        if (t == 0) {
            if (wave == 0) {
                if (lane < L_) part_lds[lane] = b2f(e16[(L_ - 1) * L_ + lane]);
                if (lane == 0) {
                    int tg = tgt_lds[0];
                    tgt_e_s = b2f(e16[(L_ - 1) * L_ + tg]);
                    prev_s  = tg;
                }
            }
            __syncthreads();
        } else {
            const int j = lane;
            if (j < L_) {
                float vv[13];
                float pm = -1e30f;
#pragma unroll
                for (int c = 0; c < 13; ++c) {
                    const int i  = i_begin + c;
                    const int ii = (i < L_) ? i : 0;
                    float v = (i < L_) ? (b2f(e16[ii * L_ + j]) + part_lds[ii]) : -1e30f;
                    vv[c] = v;
                    pm = fmaxf(pm, v);
                }
                float ps = 0.f;
#pragma unroll
                for (int c = 0; c < 13; ++c) ps += __expf(vv[c] - pm);
                pm_lds[wave][j] = pm;
                ps_lds[wave][j] = ps;
            }
            __syncthreads();                 // partials ready; part_lds reads done
            if (wave == 0 && j < L_) {
                float M = pm_lds[0][j];
#pragma unroll
                for (int w = 1; w < 4; ++w) M = fmaxf(M, pm_lds[w][j]);
                float S = 0.f;
#pragma unroll
                for (int w = 0; w < 4; ++w) S += ps_lds[w][j] * __expf(pm_lds[w][j] - M);
                const float pn   = M + __logf(S);
                const float po   = part_lds[j];
                const float mval = mask_lds[t];
                part_lds[j] = po + (pn - po) * mval;
            }
            if (tid == 0) {
                int tg = tgt_lds[t];
                tgt_e_s += b2f(e16[prev_s * L_ + tg]);
                prev_s = tg;
            }
            // no third barrier: next iter writes the other buffer; part_lds
            // update is protected by next iter's top __syncthreads()
        }
        buf ^= 1;
    }
    __syncthreads();

    if (tid < L_) part_ws[b * L_ + tid] = part_lds[tid];
    if (tid == 0) {
        tgt_ws[b]  = tgt_e_s;
        prev_ws[b] = prev_s;
        if (t0 + Tc == T_) {   // final chunk: emit loss
            float M = part_lds[0];
            for (int jj = 1; jj < L_; ++jj) M = fmaxf(M, part_lds[jj]);
            float S = 0.f;
            for (int jj = 0; jj < L_; ++jj) S += __expf(part_lds[jj] - M);
            out[b] = M + __logf(S) - tgt_e_s;
        }
    }
}

// ---------------------------------------------------------------------------
extern "C" void kernel_launch(void* const* d_in, const int* in_sizes, int n_in,
                              void* d_out, int out_size, void* d_ws, size_t ws_size,
                              hipStream_t stream)
{
    (void)in_sizes; (void)n_in; (void)out_size;
    const float* x       = (const float*)d_in[0];
    const float* mask    = (const float*)d_in[1];
    const int*   target  = (const int*)d_in[2];
    const float* state_W = (const float*)d_in[3];
    const float* state_b = (const float*)d_in[4];
    const float* trans_W = (const float*)d_in[5];
    const float* trans_b = (const float*)d_in[6];
    float* out = (float*)d_out;

    char* ws = (char*)d_ws;
    size_t off = 0;
    auto alloc = [&](size_t bytes) -> void* {
        void* p = ws + off;
        off = (off + bytes + 255) & ~(size_t)255;
        return p;
    };

    __hip_bfloat16* Wt   = (__hip_bfloat16*)alloc((size_t)NPAD_ * K_ * 2);
    float*          bias = (float*)alloc((size_t)NPAD_ * 4);
    __hip_bfloat16* xb   = (__hip_bfloat16*)alloc((size_t)B_ * T_ * K_ * 2);
    float*          part = (float*)alloc((size_t)B_ * L_ * 4);
    float*          tgte = (float*)alloc((size_t)B_ * 4);
    int*            prev = (int*)alloc((size_t)B_ * 4);
    const size_t fixed = off;

    // Chunk T so the (row-padded) energy buffer fits in ws
    int Tc = 256;
    while (Tc > 4 && fixed + (size_t)Tc * B_ * NPAD_ * 2 > ws_size) Tc >>= 1;
    __hip_bfloat16* echunk = (__hip_bfloat16*)alloc((size_t)Tc * B_ * NPAD_ * 2);
    int TcShift = 0;
    while ((1 << TcShift) < Tc) ++TcShift;

    prep_w<<<dim3(K_), 256, 0, stream>>>(trans_W, trans_b, state_W, state_b, Wt, bias);
    prep_x<<<dim3(4096), 256, 0, stream>>>(x, xb, B_ * T_ * K_);

    for (int t0 = 0; t0 < T_; t0 += Tc) {
        gemm_energy<<<dim3(NPAD_ / 64, Tc), 256, 0, stream>>>(
            xb, Wt, bias, mask, echunk, t0, Tc, TcShift);
        scan_kernel<<<dim3(B_), 256, 0, stream>>>(
            echunk, mask, target, part, tgte, prev, out, t0, Tc);
    }
}

// Round 3
// 435.154 us; speedup vs baseline: 2.8423x; 1.3096x over previous
//
#include <hip/hip_runtime.h>
#include <hip/hip_bf16.h>

#define B_    64
#define T_    256
#define K_    256
#define L_    51
#define LL_   2601
#define RS_   56      // row stride (i-dim) inside one P/energy tile, 112B = 16B-aligned
#define NG_   2880    // GEMM N: 51*56 = 2856 padded to 45*64
#define PST_  3584    // P tile stride per (b,t): 64 rows * 56, bf16 elems

typedef __bf16 bf16x8 __attribute__((ext_vector_type(8)));
typedef float  f32x4  __attribute__((ext_vector_type(4)));
typedef unsigned int u32x4 __attribute__((ext_vector_type(4)));
typedef u32x4 __attribute__((may_alias)) u32x4_a;

static __device__ __forceinline__ bf16x8 as_bf16x8(u32x4 u) {
    return __builtin_bit_cast(bf16x8, u);
}

// ---------------------------------------------------------------------------
// Prep: W't[n'][k], n' = j*56 + i  <->  trans col o = i*51+j, plus state_W[.,j]
// ---------------------------------------------------------------------------
__global__ void prep_w(const float* __restrict__ trans_W, const float* __restrict__ trans_b,
                       const float* __restrict__ state_W, const float* __restrict__ state_b,
                       __hip_bfloat16* __restrict__ Wt, float* __restrict__ bias)
{
    const int k = blockIdx.x;  // 0..255
    for (int n = threadIdx.x; n < NG_; n += blockDim.x) {
        const int j = n / RS_;
        const int i = n - j * RS_;
        const bool valid = (i < L_) && (j < L_);
        float w = 0.f;
        if (valid) w = trans_W[(size_t)k * LL_ + i * L_ + j] + state_W[k * L_ + j];
        Wt[(size_t)n * K_ + k] = __float2bfloat16(w);
        if (k == 0) {
            float bv = 0.f;
            if (valid) bv = trans_b[i * L_ + j] + state_b[j];
            bias[n] = bv;
        }
    }
}

__global__ void prep_x(const float* __restrict__ x, __hip_bfloat16* __restrict__ xb, int ntot)
{
    for (int idx = blockIdx.x * blockDim.x + threadIdx.x; idx < ntot;
         idx += gridDim.x * blockDim.x)
        xb[idx] = __float2bfloat16(x[idx]);
}

// zero the pad region [NG_, PST_) of every (b,t) tile of P
__global__ void zero_pad(__hip_bfloat16* __restrict__ P, int nBT)
{
    const int tot = nBT * (PST_ - NG_);
    for (int idx = blockIdx.x * blockDim.x + threadIdx.x; idx < tot;
         idx += gridDim.x * blockDim.x) {
        const int m = idx / (PST_ - NG_);
        const int o = idx - m * (PST_ - NG_);
        P[(size_t)m * PST_ + NG_ + o] = __float2bfloat16(0.f);
    }
}

// ---------------------------------------------------------------------------
// GEMM + exp epilogue: P[m][j*56+i] = exp((x[m]·W'[:,n'] + b'[n']) * mask(m))
// for i<51 && j<51, else 0. MFMA 16x16x32 bf16, 4 waves, grid (45, Tc).
// ---------------------------------------------------------------------------
__global__ __launch_bounds__(256) void gemm_energy(
    const __hip_bfloat16* __restrict__ xb,   // [B*T][K]
    const __hip_bfloat16* __restrict__ Wt,   // [NG][K]
    const float* __restrict__ bias,          // [NG]
    const float* __restrict__ mask,          // [B][T]
    __hip_bfloat16* __restrict__ P,          // [B*Tc][PST]
    int t0, int Tc, int TcShift)
{
    const int lane = threadIdx.x & 63;
    const int wave = threadIdx.x >> 6;
    const int quad = lane >> 4;
    const int l16  = lane & 15;
    const int m0 = (blockIdx.y * 4 + wave) * 16;
    const int n0 = blockIdx.x * 64;

    const int am  = m0 + l16;
    const int ab  = am >> TcShift;
    const int atl = am & (Tc - 1);
    const u32x4* ap = reinterpret_cast<const u32x4*>(xb + (size_t)(ab * T_ + t0 + atl) * K_);

    const u32x4* bp[4];
#pragma unroll
    for (int f = 0; f < 4; ++f)
        bp[f] = reinterpret_cast<const u32x4*>(Wt + (size_t)(n0 + f * 16 + l16) * K_);

    f32x4 acc[4] = {};
#pragma unroll
    for (int kk = 0; kk < 8; ++kk) {
        bf16x8 a = as_bf16x8(ap[kk * 4 + quad]);
#pragma unroll
        for (int f = 0; f < 4; ++f) {
            bf16x8 bfr = as_bf16x8(bp[f][kk * 4 + quad]);
            acc[f] = __builtin_amdgcn_mfma_f32_16x16x32_bf16(a, bfr, acc[f], 0, 0, 0);
        }
    }

    // C/D layout: col = lane&15, row = quad*4 + r
#pragma unroll
    for (int r = 0; r < 4; ++r) {
        const int m  = m0 + quad * 4 + r;
        const int b  = m >> TcShift;
        const int tl = m & (Tc - 1);
        const float mval = mask[b * T_ + t0 + tl];
#pragma unroll
        for (int f = 0; f < 4; ++f) {
            const int n = n0 + f * 16 + l16;
            const int j = n / RS_;
            const int i = n - j * RS_;
            float v = 0.f;
            if (i < L_ && j < L_) v = __expf((acc[f][r] + bias[n]) * mval);
            P[(size_t)m * PST_ + n] = __float2bfloat16(v);
        }
    }
}

// ---------------------------------------------------------------------------
// Target-path energy: tgt_e[b] = sum_t log P[b,t][tgt_t*56 + prev]
// ---------------------------------------------------------------------------
__global__ __launch_bounds__(64) void tgt_kernel(
    const __hip_bfloat16* __restrict__ P, const int* __restrict__ target,
    float* __restrict__ tgt_ws, int t0, int Tc)
{
    const int b = blockIdx.x, lane = threadIdx.x;
    float s = 0.f;
    for (int tl = lane; tl < Tc; tl += 64) {
        const int t = t0 + tl;
        const int j = target[b * T_ + t];
        const int i = (t == 0) ? (L_ - 1) : target[b * T_ + t - 1];
        const float pval = __bfloat162float(P[(size_t)(b * Tc + tl) * PST_ + j * RS_ + i]);
        s += __logf(pval);
    }
#pragma unroll
    for (int d = 1; d < 64; d <<= 1) s += __shfl_xor(s, d);
    if (lane == 0) {
        if (t0 == 0) tgt_ws[b] = s;
        else         tgt_ws[b] += s;
    }
}

// ---------------------------------------------------------------------------
// Linear-space scan: one wave per chain. p_t = P_t^T p_{t-1} via MFMA matvec.
// B-frags prefetched from global 2 steps ahead; A-frag via tiny LDS roundtrip.
// ---------------------------------------------------------------------------
__global__ __launch_bounds__(64) void scan_mv(
    const __hip_bfloat16* __restrict__ P,    // [B*Tc][PST]
    const float* __restrict__ mask,
    float* __restrict__ p_ws,                // [B][64]
    float* __restrict__ ls_ws,               // [B]
    const float* __restrict__ tgt_ws,        // [B]
    float* __restrict__ out,                 // [B]
    int t0, int Tc)
{
    __shared__ __align__(16) unsigned short p_arr[64];  // p~ as bf16 bits
    __shared__ float mask_lds[T_];

    const int b    = blockIdx.x;
    const int lane = threadIdx.x;
    const int quad = lane >> 4;
    const int l16  = lane & 15;

    for (int i = lane; i < T_; i += 64) mask_lds[i] = mask[b * T_ + i];

    float pv[4];
    float logscale;
    if (t0 == 0) {
        p_arr[lane] = (lane == 50) ? (unsigned short)0x3F80 : (unsigned short)0;
        pv[0] = pv[1] = pv[2] = pv[3] = 0.f;
        logscale = 0.f;
    } else {
#pragma unroll
        for (int f = 0; f < 4; ++f) pv[f] = p_ws[b * 64 + f * 16 + l16];
        logscale = ls_ws[b];
        if (quad == 0) {
#pragma unroll
            for (int f = 0; f < 4; ++f)
                p_arr[f * 16 + l16] =
                    __builtin_bit_cast(unsigned short, __float2bfloat16(pv[f]));
        }
    }
    __syncthreads();   // single wave: ~free; orders p_arr init vs first read

    // global u32x4 offsets of the 8 B-fragments within one tile
    int off[8];
#pragma unroll
    for (int f = 0; f < 4; ++f) {
#pragma unroll
        for (int ks = 0; ks < 2; ++ks)
            off[f * 2 + ks] = (f * 16 + l16) * 7 + ks * 4 + quad;
    }
    const u32x4* gp = reinterpret_cast<const u32x4*>(P) + (size_t)b * Tc * (PST_ / 8);

    u32x4 sA[8], sB[8];
#pragma unroll
    for (int q = 0; q < 8; ++q) sA[q] = gp[off[q]];
#pragma unroll
    for (int q = 0; q < 8; ++q) sB[q] = gp[448 + off[q]];

    const u32x4_a* pa = reinterpret_cast<const u32x4_a*>(p_arr);

    auto step = [&](u32x4 (&st)[8], int tl) {
        bf16x8 a0 = as_bf16x8(pa[quad]);       // p~[quad*8 .. +7]
        bf16x8 a1 = as_bf16x8(pa[4 + quad]);   // p~[32+quad*8 .. +7]
        f32x4 acc[4] = {};
#pragma unroll
        for (int f = 0; f < 4; ++f) {
            acc[f] = __builtin_amdgcn_mfma_f32_16x16x32_bf16(a0, as_bf16x8(st[f * 2 + 0]), acc[f], 0, 0, 0);
            acc[f] = __builtin_amdgcn_mfma_f32_16x16x32_bf16(a1, as_bf16x8(st[f * 2 + 1]), acc[f], 0, 0, 0);
        }
        const float m = (t0 + tl == 0) ? 1.f : mask_lds[t0 + tl];
#pragma unroll
        for (int f = 0; f < 4; ++f) pv[f] += (acc[f][0] - pv[f]) * m;

        if (((tl & 3) == 3) || (tl == Tc - 1)) {        // rescale
            float mx = fmaxf(fmaxf(pv[0], pv[1]), fmaxf(pv[2], pv[3]));
#pragma unroll
            for (int d = 1; d < 16; d <<= 1) mx = fmaxf(mx, __shfl_xor(mx, d));
            const float inv = 1.f / mx;
            logscale += __logf(mx);
#pragma unroll
            for (int f = 0; f < 4; ++f) pv[f] *= inv;
        }
        if (quad == 0) {
#pragma unroll
            for (int f = 0; f < 4; ++f)
                p_arr[f * 16 + l16] =
                    __builtin_bit_cast(unsigned short, __float2bfloat16(pv[f]));
        }
        __syncthreads();   // single wave: orders p_arr write -> next read
    };

    for (int tl = 0; tl < Tc; tl += 2) {
        step(sA, tl);
        if (tl + 2 < Tc) {
            const u32x4* g = gp + (size_t)(tl + 2) * 448;
#pragma unroll
            for (int q = 0; q < 8; ++q) sA[q] = g[off[q]];
        }
        step(sB, tl + 1);
        if (tl + 3 < Tc) {
            const u32x4* g = gp + (size_t)(tl + 3) * 448;
#pragma unroll
            for (int q = 0; q < 8; ++q) sB[q] = g[off[q]];
        }
    }

    if (t0 + Tc == T_) {
        float s = pv[0] + pv[1] + pv[2] + pv[3];
#pragma unroll
        for (int d = 1; d < 16; d <<= 1) s += __shfl_xor(s, d);
        if (lane == 0) out[b] = logscale + __logf(s) - tgt_ws[b];
    } else {
        if (quad == 0) {
#pragma unroll
            for (int f = 0; f < 4; ++f) p_ws[b * 64 + f * 16 + l16] = pv[f];
        }
        if (lane == 0) ls_ws[b] = logscale;
    }
}

// ---------------------------------------------------------------------------
extern "C" void kernel_launch(void* const* d_in, const int* in_sizes, int n_in,
                              void* d_out, int out_size, void* d_ws, size_t ws_size,
                              hipStream_t stream)
{
    (void)in_sizes; (void)n_in; (void)out_size;
    const float* x       = (const float*)d_in[0];
    const float* mask    = (const float*)d_in[1];
    const int*   target  = (const int*)d_in[2];
    const float* state_W = (const float*)d_in[3];
    const float* state_b = (const float*)d_in[4];
    const float* trans_W = (const float*)d_in[5];
    const float* trans_b = (const float*)d_in[6];
    float* out = (float*)d_out;

    char* ws = (char*)d_ws;
    size_t off = 0;
    auto alloc = [&](size_t bytes) -> void* {
        void* p = ws + off;
        off = (off + bytes + 255) & ~(size_t)255;
        return p;
    };

    __hip_bfloat16* Wt   = (__hip_bfloat16*)alloc((size_t)NG_ * K_ * 2);
    float*          bias = (float*)alloc((size_t)NG_ * 4);
    __hip_bfloat16* xb   = (__hip_bfloat16*)alloc((size_t)B_ * T_ * K_ * 2);
    float*          p_ws = (float*)alloc((size_t)B_ * 64 * 4);
    float*          ls   = (float*)alloc((size_t)B_ * 4);
    float*          tgte = (float*)alloc((size_t)B_ * 4);
    const size_t fixed = off;

    int Tc = 256;
    while (Tc > 4 && fixed + (size_t)Tc * B_ * PST_ * 2 > ws_size) Tc >>= 1;
    __hip_bfloat16* P = (__hip_bfloat16*)alloc((size_t)Tc * B_ * PST_ * 2);
    int TcShift = 0;
    while ((1 << TcShift) < Tc) ++TcShift;

    prep_w<<<dim3(K_), 256, 0, stream>>>(trans_W, trans_b, state_W, state_b, Wt, bias);
    prep_x<<<dim3(4096), 256, 0, stream>>>(x, xb, B_ * T_ * K_);
    zero_pad<<<dim3(2048), 256, 0, stream>>>(P, B_ * Tc);

    for (int t0 = 0; t0 < T_; t0 += Tc) {
        gemm_energy<<<dim3(NG_ / 64, Tc), 256, 0, stream>>>(
            xb, Wt, bias, mask, P, t0, Tc, TcShift);
        tgt_kernel<<<dim3(B_), 64, 0, stream>>>(P, target, tgte, t0, Tc);
        scan_mv<<<dim3(B_), 64, 0, stream>>>(P, mask, p_ws, ls, tgte, out, t0, Tc);
    }
}

// Round 4
// 253.905 us; speedup vs baseline: 4.8713x; 1.7138x over previous
//
#include <hip/hip_runtime.h>
#include <hip/hip_bf16.h>

#define B_    64
#define T_    256
#define K_    256
#define L_    51
#define LL_   2601
#define RS_   56      // row stride (i-dim) inside one P tile, 112B = 16B-aligned
#define NG_   2944    // GEMM N: 51*56 = 2856 padded to 23*128
#define PST_  3584    // P tile stride per (b,t): 64 rows * 56 bf16 elems
#define MT_   128
#define NT_   128

typedef __bf16 bf16x8 __attribute__((ext_vector_type(8)));
typedef float  f32x4  __attribute__((ext_vector_type(4)));
typedef unsigned int u32x4 __attribute__((ext_vector_type(4)));
typedef u32x4 __attribute__((may_alias)) u32x4_a;

static __device__ __forceinline__ bf16x8 as_bf16x8(u32x4 u) {
    return __builtin_bit_cast(bf16x8, u);
}

static __device__ __forceinline__ void gld_lds16(const void* g, void* l) {
    __builtin_amdgcn_global_load_lds(
        (const __attribute__((address_space(1))) unsigned int*)g,
        (__attribute__((address_space(3))) unsigned int*)l, 16, 0, 0);
}

// ---------------------------------------------------------------------------
// prep_w: Wt[n][k] = trans_W[k][i*51+j] + state_W[k][j],  n = j*56+i, bf16.
// One thread owns (n, 64-k-range) -> coalesced 128B contiguous writes.
// ---------------------------------------------------------------------------
__global__ __launch_bounds__(256) void prep_w(
    const float* __restrict__ trans_W, const float* __restrict__ trans_b,
    const float* __restrict__ state_W, const float* __restrict__ state_b,
    __hip_bfloat16* __restrict__ Wt, float* __restrict__ bias)
{
    const int n  = blockIdx.x * 64 + (threadIdx.x >> 2);
    const int kq = (threadIdx.x & 3) * 64;
    const int j  = n / RS_;
    const int i  = n - j * RS_;
    const bool valid = (i < L_) && (j < L_);
    const int o = i * L_ + j;

    __hip_bfloat16 tmp[64];
#pragma unroll
    for (int kk = 0; kk < 64; ++kk) {
        const int k = kq + kk;
        float w = valid ? (trans_W[(size_t)k * LL_ + o] + state_W[k * L_ + j]) : 0.f;
        tmp[kk] = __float2bfloat16(w);
    }
    u32x4* dst = (u32x4*)(Wt + (size_t)n * K_ + kq);
    const u32x4* src = (const u32x4*)tmp;
#pragma unroll
    for (int q = 0; q < 8; ++q) dst[q] = src[q];

    if ((threadIdx.x & 3) == 0)
        bias[n] = valid ? (trans_b[o] + state_b[j]) : 0.f;
}

// x fp32 -> bf16, vectorized
__global__ void prep_x(const float4* __restrict__ x4, ushort4* __restrict__ xb4, int n4)
{
    for (int idx = blockIdx.x * blockDim.x + threadIdx.x; idx < n4;
         idx += gridDim.x * blockDim.x) {
        float4 v = x4[idx];
        ushort4 o;
        o.x = __builtin_bit_cast(unsigned short, __float2bfloat16(v.x));
        o.y = __builtin_bit_cast(unsigned short, __float2bfloat16(v.y));
        o.z = __builtin_bit_cast(unsigned short, __float2bfloat16(v.z));
        o.w = __builtin_bit_cast(unsigned short, __float2bfloat16(v.w));
        xb4[idx] = o;
    }
}

// zero the pad region [NG_, PST_) of every (b,t) tile of P, 16B stores
__global__ void zero_pad(u32x4* __restrict__ P16, int nBT)
{
    const int per = (PST_ - NG_) / 8;          // 80 u32x4 per tile
    const int tot = nBT * per;
    const u32x4 z = {};
    for (int idx = blockIdx.x * blockDim.x + threadIdx.x; idx < tot;
         idx += gridDim.x * blockDim.x) {
        const int m = idx / per;
        const int q = idx - m * per;
        P16[(size_t)m * (PST_ / 8) + (NG_ / 8) + q] = z;
    }
}

// ---------------------------------------------------------------------------
// GEMM + exp epilogue, LDS-staged (m97-style).
// Block 128x128, 4 waves each 64x64. K=256 in two 128-halves, single LDS buf
// (64 KB -> 2 blocks/CU). XOR swizzle (chunk ^ row&15) -> 2-way LDS reads.
// P[m][j*56+i] = exp((x[m]·W' + b') * mask(m)) for i<51&&j<51, else 0.
// ---------------------------------------------------------------------------
__global__ __launch_bounds__(256) void gemm_energy(
    const __hip_bfloat16* __restrict__ xb,   // [B*T][K]
    const __hip_bfloat16* __restrict__ Wt,   // [NG][K]
    const float* __restrict__ bias,          // [NG]
    const float* __restrict__ mask,          // [B][T]
    __hip_bfloat16* __restrict__ P,          // [B*Tc][PST]
    int t0, int Tc, int TcShift)
{
    __shared__ __align__(16) __hip_bfloat16 As[MT_ * 128];  // 32 KB (one K-half)
    __shared__ __align__(16) __hip_bfloat16 Bs[NT_ * 128];  // 32 KB

    const int tid  = threadIdx.x;
    const int lane = tid & 63;
    const int wv   = tid >> 6;
    const int quad = lane >> 4;
    const int l16  = lane & 15;
    const int m0 = blockIdx.y * MT_;
    const int n0 = blockIdx.x * NT_;
    const int mrow0 = (wv >> 1) * 64;
    const int ncol0 = (wv & 1) * 64;

    // staging geometry: issue 'it' covers LDS rows it*16 + wv*4 + lane/16
    const int srow = wv * 4 + (lane >> 4);
    const int spos = lane & 15;              // 16B position within 256B row

    f32x4 acc[4][4] = {};

    for (int kp = 0; kp < 2; ++kp) {
        if (kp) __syncthreads();             // LDS reuse
#pragma unroll
        for (int it = 0; it < 8; ++it) {
            const int r  = it * 16 + srow;
            const int kc = spos ^ (r & 15);  // swizzled source chunk
            const int ma = m0 + r;
            const int rg = (ma >> TcShift) * T_ + t0 + (ma & (Tc - 1));
            gld_lds16((const char*)xb + (size_t)rg * 512 + kp * 256 + kc * 16,
                      (char*)As + it * 4096 + wv * 1024);
            gld_lds16((const char*)Wt + (size_t)(n0 + r) * 512 + kp * 256 + kc * 16,
                      (char*)Bs + it * 4096 + wv * 1024);
        }
        asm volatile("s_waitcnt vmcnt(0)" ::: "memory");
        __syncthreads();

        const u32x4_a* Av = (const u32x4_a*)As;
        const u32x4_a* Bv = (const u32x4_a*)Bs;
#pragma unroll
        for (int kk = 0; kk < 4; ++kk) {
            bf16x8 af[4], bfr[4];
#pragma unroll
            for (int f = 0; f < 4; ++f) {
                const int ra = mrow0 + f * 16 + l16;
                af[f]  = as_bf16x8(Av[ra * 16 + ((kk * 4 + quad) ^ (ra & 15))]);
                const int rb = ncol0 + f * 16 + l16;
                bfr[f] = as_bf16x8(Bv[rb * 16 + ((kk * 4 + quad) ^ (rb & 15))]);
            }
#pragma unroll
            for (int mf = 0; mf < 4; ++mf)
#pragma unroll
                for (int nf = 0; nf < 4; ++nf)
                    acc[mf][nf] = __builtin_amdgcn_mfma_f32_16x16x32_bf16(
                        af[mf], bfr[nf], acc[mf][nf], 0, 0, 0);
        }
    }

    // epilogue: per-nf column info (n independent of mf/r)
    float bv[4]; bool val[4]; int ncol[4];
#pragma unroll
    for (int nf = 0; nf < 4; ++nf) {
        const int n = n0 + ncol0 + nf * 16 + l16;
        const int j = n / RS_;
        const int i = n - j * RS_;
        ncol[nf] = n;
        val[nf]  = (i < L_) && (j < L_);
        bv[nf]   = bias[n];
    }
#pragma unroll
    for (int mf = 0; mf < 4; ++mf) {
#pragma unroll
        for (int r = 0; r < 4; ++r) {
            const int mloc = m0 + mrow0 + mf * 16 + quad * 4 + r;
            const int bb = mloc >> TcShift;
            const int tl = mloc & (Tc - 1);
            const float mval = mask[bb * T_ + t0 + tl];
            __hip_bfloat16* prow = P + (size_t)mloc * PST_;
#pragma unroll
            for (int nf = 0; nf < 4; ++nf) {
                float v = val[nf] ? __expf((acc[mf][nf][r] + bv[nf]) * mval) : 0.f;
                prow[ncol[nf]] = __float2bfloat16(v);
            }
        }
    }
}

// ---------------------------------------------------------------------------
// Target-path energy: tgt_e[b] = sum_t log P[b,t][tgt_t*56 + prev]
// ---------------------------------------------------------------------------
__global__ __launch_bounds__(64) void tgt_kernel(
    const __hip_bfloat16* __restrict__ P, const int* __restrict__ target,
    float* __restrict__ tgt_ws, int t0, int Tc)
{
    const int b = blockIdx.x, lane = threadIdx.x;
    float s = 0.f;
    for (int tl = lane; tl < Tc; tl += 64) {
        const int t = t0 + tl;
        const int j = target[b * T_ + t];
        const int i = (t == 0) ? (L_ - 1) : target[b * T_ + t - 1];
        const float pval = __bfloat162float(P[(size_t)(b * Tc + tl) * PST_ + j * RS_ + i]);
        s += __logf(pval);
    }
#pragma unroll
    for (int d = 1; d < 64; d <<= 1) s += __shfl_xor(s, d);
    if (lane == 0) {
        if (t0 == 0) tgt_ws[b] = s;
        else         tgt_ws[b] += s;
    }
}

// ---------------------------------------------------------------------------
// Linear-space scan: one wave per chain. p_t = P_t^T p_{t-1} via MFMA matvec.
// Depth-4 register prefetch (per-step ~230cyc x4 covers L3/HBM latency).
// ---------------------------------------------------------------------------
__global__ __launch_bounds__(64, 1) void scan_mv(
    const __hip_bfloat16* __restrict__ P,    // [B*Tc][PST]
    const float* __restrict__ mask,
    float* __restrict__ p_ws,                // [B][64]
    float* __restrict__ ls_ws,               // [B]
    const float* __restrict__ tgt_ws,        // [B]
    float* __restrict__ out,                 // [B]
    int t0, int Tc)
{
    __shared__ __align__(16) unsigned short p_arr[64];  // p~ as bf16 bits
    __shared__ float mask_lds[T_];

    const int b    = blockIdx.x;
    const int lane = threadIdx.x;
    const int quad = lane >> 4;
    const int l16  = lane & 15;

    for (int i = lane; i < T_; i += 64) mask_lds[i] = mask[b * T_ + i];

    float pv[4];
    float logscale;
    if (t0 == 0) {
        p_arr[lane] = (lane == 50) ? (unsigned short)0x3F80 : (unsigned short)0;
        pv[0] = pv[1] = pv[2] = pv[3] = 0.f;
        logscale = 0.f;
    } else {
#pragma unroll
        for (int f = 0; f < 4; ++f) pv[f] = p_ws[b * 64 + f * 16 + l16];
        logscale = ls_ws[b];
        if (quad == 0) {
#pragma unroll
            for (int f = 0; f < 4; ++f)
                p_arr[f * 16 + l16] =
                    __builtin_bit_cast(unsigned short, __float2bfloat16(pv[f]));
        }
    }
    __syncthreads();

    // global u32x4 offsets of the 8 B-fragments within one tile
    int off[8];
#pragma unroll
    for (int f = 0; f < 4; ++f)
#pragma unroll
        for (int ks = 0; ks < 2; ++ks)
            off[f * 2 + ks] = (f * 16 + l16) * 7 + ks * 4 + quad;

    const u32x4* gp = reinterpret_cast<const u32x4*>(P) + (size_t)b * Tc * (PST_ / 8);
    const u32x4_a* pa = reinterpret_cast<const u32x4_a*>(p_arr);

    u32x4 s0[8], s1[8], s2[8], s3[8];
    auto fetch = [&](u32x4 (&st)[8], int tl) {
        const u32x4* g = gp + (size_t)tl * (PST_ / 8);
#pragma unroll
        for (int q = 0; q < 8; ++q) st[q] = g[off[q]];
    };
    fetch(s0, 0); fetch(s1, 1); fetch(s2, 2); fetch(s3, 3);

    auto step = [&](u32x4 (&st)[8], int tl) {
        bf16x8 a0 = as_bf16x8(pa[quad]);       // p~[quad*8 .. +7]
        bf16x8 a1 = as_bf16x8(pa[4 + quad]);   // p~[32+quad*8 .. +7]
        f32x4 acc[4] = {};
#pragma unroll
        for (int f = 0; f < 4; ++f) {
            acc[f] = __builtin_amdgcn_mfma_f32_16x16x32_bf16(a0, as_bf16x8(st[f * 2 + 0]), acc[f], 0, 0, 0);
            acc[f] = __builtin_amdgcn_mfma_f32_16x16x32_bf16(a1, as_bf16x8(st[f * 2 + 1]), acc[f], 0, 0, 0);
        }
        const float m = (t0 + tl == 0) ? 1.f : mask_lds[t0 + tl];
#pragma unroll
        for (int f = 0; f < 4; ++f) pv[f] += (acc[f][0] - pv[f]) * m;

        if (((tl & 3) == 3) || (tl == Tc - 1)) {        // rescale
            float mx = fmaxf(fmaxf(pv[0], pv[1]), fmaxf(pv[2], pv[3]));
#pragma unroll
            for (int d = 1; d < 16; d <<= 1) mx = fmaxf(mx, __shfl_xor(mx, d));
            const float inv = 1.f / mx;
            logscale += __logf(mx);
#pragma unroll
            for (int f = 0; f < 4; ++f) pv[f] *= inv;
        }
        if (quad == 0) {
#pragma unroll
            for (int f = 0; f < 4; ++f)
                p_arr[f * 16 + l16] =
                    __builtin_bit_cast(unsigned short, __float2bfloat16(pv[f]));
        }
        __syncthreads();
    };

    for (int tl = 0; tl < Tc; tl += 4) {
        step(s0, tl);     if (tl + 4 < Tc) fetch(s0, tl + 4);
        step(s1, tl + 1); if (tl + 5 < Tc) fetch(s1, tl + 5);
        step(s2, tl + 2); if (tl + 6 < Tc) fetch(s2, tl + 6);
        step(s3, tl + 3); if (tl + 7 < Tc) fetch(s3, tl + 7);
    }

    if (t0 + Tc == T_) {
        float s = pv[0] + pv[1] + pv[2] + pv[3];
#pragma unroll
        for (int d = 1; d < 16; d <<= 1) s += __shfl_xor(s, d);
        if (lane == 0) out[b] = logscale + __logf(s) - tgt_ws[b];
    } else {
        if (quad == 0) {
#pragma unroll
            for (int f = 0; f < 4; ++f) p_ws[b * 64 + f * 16 + l16] = pv[f];
        }
        if (lane == 0) ls_ws[b] = logscale;
    }
}

// ---------------------------------------------------------------------------
extern "C" void kernel_launch(void* const* d_in, const int* in_sizes, int n_in,
                              void* d_out, int out_size, void* d_ws, size_t ws_size,
                              hipStream_t stream)
{
    (void)in_sizes; (void)n_in; (void)out_size;
    const float* x       = (const float*)d_in[0];
    const float* mask    = (const float*)d_in[1];
    const int*   target  = (const int*)d_in[2];
    const float* state_W = (const float*)d_in[3];
    const float* state_b = (const float*)d_in[4];
    const float* trans_W = (const float*)d_in[5];
    const float* trans_b = (const float*)d_in[6];
    float* out = (float*)d_out;

    char* ws = (char*)d_ws;
    size_t off = 0;
    auto alloc = [&](size_t bytes) -> void* {
        void* p = ws + off;
        off = (off + bytes + 255) & ~(size_t)255;
        return p;
    };

    __hip_bfloat16* Wt   = (__hip_bfloat16*)alloc((size_t)NG_ * K_ * 2);
    float*          bias = (float*)alloc((size_t)NG_ * 4);
    __hip_bfloat16* xb   = (__hip_bfloat16*)alloc((size_t)B_ * T_ * K_ * 2);
    float*          p_ws = (float*)alloc((size_t)B_ * 64 * 4);
    float*          ls   = (float*)alloc((size_t)B_ * 4);
    float*          tgte = (float*)alloc((size_t)B_ * 4);
    const size_t fixed = off;

    int Tc = 256;
    while (Tc > 4 && fixed + (size_t)Tc * B_ * PST_ * 2 + 256 > ws_size) Tc >>= 1;
    __hip_bfloat16* P = (__hip_bfloat16*)alloc((size_t)Tc * B_ * PST_ * 2);
    int TcShift = 0;
    while ((1 << TcShift) < Tc) ++TcShift;

    prep_w<<<dim3(NG_ / 64), 256, 0, stream>>>(trans_W, trans_b, state_W, state_b, Wt, bias);
    prep_x<<<dim3(2048), 256, 0, stream>>>((const float4*)x, (ushort4*)xb, B_ * T_ * K_ / 4);
    zero_pad<<<dim3(2048), 256, 0, stream>>>((u32x4*)P, B_ * Tc);

    for (int t0 = 0; t0 < T_; t0 += Tc) {
        gemm_energy<<<dim3(NG_ / NT_, (B_ * Tc) / MT_), 256, 0, stream>>>(
            xb, Wt, bias, mask, P, t0, Tc, TcShift);
        tgt_kernel<<<dim3(B_), 64, 0, stream>>>(P, target, tgte, t0, Tc);
        scan_mv<<<dim3(B_), 64, 0, stream>>>(P, mask, p_ws, ls, tgte, out, t0, Tc);
    }
}

// Round 5
// 230.384 us; speedup vs baseline: 5.3687x; 1.1021x over previous
//
#include <hip/hip_runtime.h>
#include <hip/hip_bf16.h>

#define B_    64
#define T_    256
#define K_    256
#define L_    51
#define LL_   2601
#define RS_   64      // row stride inside one tile
#define NG_   3328    // GEMM N: 52*64 (j rows 0..51; row 51 zero)
#define PST_  4096    // tile stride per (b,t): 64 rows * 64 elems
#define MT_   128
#define NT_   128

typedef __bf16 bf16x8 __attribute__((ext_vector_type(8)));
typedef float  f32x4  __attribute__((ext_vector_type(4)));
typedef unsigned int u32x4 __attribute__((ext_vector_type(4)));
typedef u32x4 __attribute__((may_alias)) u32x4_a;

static __device__ __forceinline__ bf16x8 as_bf16x8(u32x4 u) {
    return __builtin_bit_cast(bf16x8, u);
}
static __device__ __forceinline__ unsigned short bf16bits(float x) {
    return __builtin_bit_cast(unsigned short, __float2bfloat16(x));
}
static __device__ __forceinline__ void gld_lds16(const void* g, void* l) {
    __builtin_amdgcn_global_load_lds(
        (const __attribute__((address_space(1))) unsigned int*)g,
        (__attribute__((address_space(3))) unsigned int*)l, 16, 0, 0);
}

// DPP reduction over the 16 l16-lanes (valid when values replicated per quad)
#define DPP_STEP(v, OP, CTRL)                                                   \
    {                                                                           \
        int _x = __builtin_bit_cast(int, v);                                    \
        float _o = __builtin_bit_cast(                                          \
            float, __builtin_amdgcn_update_dpp(_x, _x, CTRL, 0xF, 0xF, true));  \
        v = OP(v, _o);                                                          \
    }
static __device__ __forceinline__ float addf(float a, float b) { return a + b; }

// ---------------------------------------------------------------------------
// prep_w: Wt[n][k] = trans_W[k][i*51+j] + state_W[k][j],  n = j*64+i, bf16.
// ---------------------------------------------------------------------------
__global__ __launch_bounds__(256) void prep_w(
    const float* __restrict__ trans_W, const float* __restrict__ trans_b,
    const float* __restrict__ state_W, const float* __restrict__ state_b,
    __hip_bfloat16* __restrict__ Wt, float* __restrict__ bias)
{
    const int n  = blockIdx.x * 64 + (threadIdx.x >> 2);
    const int kq = (threadIdx.x & 3) * 64;
    const int j  = n >> 6;
    const int i  = n & 63;
    const bool valid = (i < L_) && (j < L_);
    const int o = i * L_ + j;

    __hip_bfloat16 tmp[64];
#pragma unroll
    for (int kk = 0; kk < 64; ++kk) {
        const int k = kq + kk;
        float w = valid ? (trans_W[(size_t)k * LL_ + o] + state_W[k * L_ + j]) : 0.f;
        tmp[kk] = __float2bfloat16(w);
    }
    u32x4* dst = (u32x4*)(Wt + (size_t)n * K_ + kq);
    const u32x4* src = (const u32x4*)tmp;
#pragma unroll
    for (int q = 0; q < 8; ++q) dst[q] = src[q];

    if ((threadIdx.x & 3) == 0)
        bias[n] = valid ? (trans_b[o] + state_b[j]) : 0.f;
}

__global__ void prep_x(const float4* __restrict__ x4, ushort4* __restrict__ xb4, int n4)
{
    for (int idx = blockIdx.x * blockDim.x + threadIdx.x; idx < n4;
         idx += gridDim.x * blockDim.x) {
        float4 v = x4[idx];
        ushort4 o;
        o.x = bf16bits(v.x); o.y = bf16bits(v.y);
        o.z = bf16bits(v.z); o.w = bf16bits(v.w);
        xb4[idx] = o;
    }
}

// zero pad region [NG_, PST_) of every (b,t) tile of P (rows j=52..63)
__global__ void zero_pad(u32x4* __restrict__ P16, int nBT)
{
    const int per = (PST_ - NG_) / 8;          // 96 chunks per tile
    const int tot = nBT * per;
    const u32x4 z = {};
    for (int idx = blockIdx.x * blockDim.x + threadIdx.x; idx < tot;
         idx += gridDim.x * blockDim.x) {
        const int m = idx / per;
        const int q = idx - m * per;
        P16[(size_t)m * (PST_ / 8) + (NG_ / 8) + q] = z;
    }
}

// ---------------------------------------------------------------------------
// GEMM + exp epilogue, LDS-staged. P tile[j][i] = exp(energy[i][j]*mask);
// masked (m==0, t>0) tiles become identity (== reference's blend-skip).
// ---------------------------------------------------------------------------
__global__ __launch_bounds__(256) void gemm_energy(
    const __hip_bfloat16* __restrict__ xb,   // [B*T][K]
    const __hip_bfloat16* __restrict__ Wt,   // [NG][K]
    const float* __restrict__ bias,          // [NG]
    const float* __restrict__ mask,          // [B][T]
    __hip_bfloat16* __restrict__ P,          // [B*Tc][PST]
    int t0, int Tc, int TcShift)
{
    __shared__ __align__(16) __hip_bfloat16 As[MT_ * 128];
    __shared__ __align__(16) __hip_bfloat16 Bs[NT_ * 128];

    const int tid  = threadIdx.x;
    const int lane = tid & 63;
    const int wv   = tid >> 6;
    const int quad = lane >> 4;
    const int l16  = lane & 15;
    const int m0 = blockIdx.y * MT_;
    const int n0 = blockIdx.x * NT_;
    const int mrow0 = (wv >> 1) * 64;
    const int ncol0 = (wv & 1) * 64;

    const int srow = wv * 4 + (lane >> 4);
    const int spos = lane & 15;

    f32x4 acc[4][4] = {};

    for (int kp = 0; kp < 2; ++kp) {
        if (kp) __syncthreads();
#pragma unroll
        for (int it = 0; it < 8; ++it) {
            const int r  = it * 16 + srow;
            const int kc = spos ^ (r & 15);
            const int ma = m0 + r;
            const int rg = (ma >> TcShift) * T_ + t0 + (ma & (Tc - 1));
            gld_lds16((const char*)xb + (size_t)rg * 512 + kp * 256 + kc * 16,
                      (char*)As + it * 4096 + wv * 1024);
            gld_lds16((const char*)Wt + (size_t)(n0 + r) * 512 + kp * 256 + kc * 16,
                      (char*)Bs + it * 4096 + wv * 1024);
        }
        asm volatile("s_waitcnt vmcnt(0)" ::: "memory");
        __syncthreads();

        const u32x4_a* Av = (const u32x4_a*)As;
        const u32x4_a* Bv = (const u32x4_a*)Bs;
#pragma unroll
        for (int kk = 0; kk < 4; ++kk) {
            bf16x8 af[4], bfr[4];
#pragma unroll
            for (int f = 0; f < 4; ++f) {
                const int ra = mrow0 + f * 16 + l16;
                af[f]  = as_bf16x8(Av[ra * 16 + ((kk * 4 + quad) ^ (ra & 15))]);
                const int rb = ncol0 + f * 16 + l16;
                bfr[f] = as_bf16x8(Bv[rb * 16 + ((kk * 4 + quad) ^ (rb & 15))]);
            }
#pragma unroll
            for (int mf = 0; mf < 4; ++mf)
#pragma unroll
                for (int nf = 0; nf < 4; ++nf)
                    acc[mf][nf] = __builtin_amdgcn_mfma_f32_16x16x32_bf16(
                        af[mf], bfr[nf], acc[mf][nf], 0, 0, 0);
        }
    }

    float bv[4]; bool val[4]; int ncol[4], ic[4], jc[4];
#pragma unroll
    for (int nf = 0; nf < 4; ++nf) {
        const int n = n0 + ncol0 + nf * 16 + l16;
        ncol[nf] = n;
        ic[nf] = n & 63;
        jc[nf] = n >> 6;
        val[nf] = (ic[nf] < L_) && (jc[nf] < L_);
        bv[nf]  = bias[n];
    }
#pragma unroll
    for (int mf = 0; mf < 4; ++mf) {
#pragma unroll
        for (int r = 0; r < 4; ++r) {
            const int mloc = m0 + mrow0 + mf * 16 + quad * 4 + r;
            const int bb = mloc >> TcShift;
            const int tl = mloc & (Tc - 1);
            const int t  = t0 + tl;
            const float mval = mask[bb * T_ + t];
            const bool idmask = (mval == 0.f) && (t != 0);
            __hip_bfloat16* prow = P + (size_t)mloc * PST_;
#pragma unroll
            for (int nf = 0; nf < 4; ++nf) {
                float v;
                if (idmask)
                    v = (val[nf] && ic[nf] == jc[nf]) ? 1.f : 0.f;
                else
                    v = val[nf] ? __expf((acc[mf][nf][r] + bv[nf]) * mval) : 0.f;
                prow[ncol[nf]] = __float2bfloat16(v);
            }
        }
    }
}

// ---------------------------------------------------------------------------
// prod_quad: Q = S4·S3·S2·S1 per (b, quad-of-t). Uses MFMA A·B^T with stage
// outputs written transposed to LDS; only S1 needs an explicit transpose.
// ---------------------------------------------------------------------------
__global__ __launch_bounds__(256) void prod_quad(
    const __hip_bfloat16* __restrict__ P,   // [B*Tc][PST]
    __hip_bfloat16* __restrict__ Q,         // [B*(Tc/4)][PST]
    int Tc)
{
    __shared__ u32x4 Sm[3][512];                           // S2..S4 swizzled
    __shared__ __align__(16) unsigned short GL[64 * 72];   // S1^T
    __shared__ __align__(16) unsigned short VT[2][64 * 72];

    const int tid  = threadIdx.x;
    const int wv   = tid >> 6;
    const int lane = tid & 63;
    const int quad = lane >> 4;
    const int l16  = lane & 15;
    const int bq = blockIdx.x;
    const int Tq = Tc >> 2;
    const int b  = bq / Tq;
    const int tq = bq - b * Tq;
    const __hip_bfloat16* tile0 = P + (size_t)(b * Tc + tq * 4) * PST_;

    // stage S2..S4 into swizzled LDS (chunk c of row r at slot r*8 + (c^(r&7)))
    for (int q = 0; q < 6; ++q) {
        const int idx  = q * 4 + wv;        // 0..23
        const int tile = idx >> 3;          // 0..2 -> tiles 1..3
        const int part = idx & 7;
        const int slot = part * 64 + lane;
        const int r    = slot >> 3;
        const int csrc = (slot & 7) ^ (r & 7);
        gld_lds16((const char*)(tile0 + (size_t)(tile + 1) * PST_) + (r * 8 + csrc) * 16,
                  (char*)&Sm[tile][part * 64]);
    }
    // load S1 and transpose into GL[i][j] (stride 72)
    const u32x4* g1 = (const u32x4*)tile0;
    u32x4 c0 = g1[tid], c1 = g1[256 + tid];
    asm volatile("s_waitcnt vmcnt(0)" ::: "memory");
    {
        const unsigned short* e0 = (const unsigned short*)&c0;
        const unsigned short* e1 = (const unsigned short*)&c1;
        int j = tid >> 3, i0 = (tid & 7) * 8;
#pragma unroll
        for (int e = 0; e < 8; ++e) GL[(i0 + e) * 72 + j] = e0[e];
        j = (256 + tid) >> 3; i0 = (tid & 7) * 8;
#pragma unroll
        for (int e = 0; e < 8; ++e) GL[(i0 + e) * 72 + j] = e1[e];
    }
    __syncthreads();

    __hip_bfloat16* qout = Q + (size_t)bq * PST_;
    const int ra = wv * 16 + l16;

#pragma unroll
    for (int st = 0; st < 3; ++st) {
        const u32x4* Sa = Sm[st];
        const unsigned short* Bbuf = (st == 0) ? GL : VT[st - 1];
        bf16x8 a[2], bb[4][2];
#pragma unroll
        for (int ks = 0; ks < 2; ++ks)
            a[ks] = as_bf16x8(Sa[ra * 8 + ((ks * 4 + quad) ^ (ra & 7))]);
#pragma unroll
        for (int nf = 0; nf < 4; ++nf) {
            const u32x4_a* brow = (const u32x4_a*)(Bbuf + (nf * 16 + l16) * 72);
#pragma unroll
            for (int ks = 0; ks < 2; ++ks) bb[nf][ks] = as_bf16x8(brow[ks * 4 + quad]);
        }
        f32x4 acc[4] = {};
#pragma unroll
        for (int nf = 0; nf < 4; ++nf) {
            acc[nf] = __builtin_amdgcn_mfma_f32_16x16x32_bf16(a[0], bb[nf][0], acc[nf], 0, 0, 0);
            acc[nf] = __builtin_amdgcn_mfma_f32_16x16x32_bf16(a[1], bb[nf][1], acc[nf], 0, 0, 0);
        }
        if (st < 2) {
#pragma unroll
            for (int nf = 0; nf < 4; ++nf) {
                const int n  = nf * 16 + l16;
                const int mm = wv * 16 + quad * 4;
#pragma unroll
                for (int pr = 0; pr < 2; ++pr) {
                    unsigned int pk = (unsigned int)bf16bits(acc[nf][pr * 2]) |
                                      ((unsigned int)bf16bits(acc[nf][pr * 2 + 1]) << 16);
                    *(unsigned int*)(&VT[st][n * 72 + mm + pr * 2]) = pk;
                }
            }
            __syncthreads();
        } else {
#pragma unroll
            for (int nf = 0; nf < 4; ++nf) {
                const int n = nf * 16 + l16;
#pragma unroll
                for (int r = 0; r < 4; ++r)
                    qout[(wv * 16 + quad * 4 + r) * RS_ + n] = __float2bfloat16(acc[nf][r]);
            }
        }
    }
}

// ---------------------------------------------------------------------------
// tgt: sum_t m_t ? log P[b,t][tgt_t*64 + prev] : 0
// ---------------------------------------------------------------------------
__global__ __launch_bounds__(64) void tgt_kernel(
    const __hip_bfloat16* __restrict__ P, const int* __restrict__ target,
    const float* __restrict__ mask, float* __restrict__ tgt_ws, int t0, int Tc)
{
    const int b = blockIdx.x, lane = threadIdx.x;
    float s = 0.f;
    for (int tl = lane; tl < Tc; tl += 64) {
        const int t = t0 + tl;
        const int j = target[b * T_ + t];
        const int i = (t == 0) ? (L_ - 1) : target[b * T_ + t - 1];
        const float m = (t == 0) ? 1.f : mask[b * T_ + t];
        if (m != 0.f) {
            const float pval = __bfloat162float(P[(size_t)(b * Tc + tl) * PST_ + j * RS_ + i]);
            s += __logf(pval);
        }
    }
#pragma unroll
    for (int d = 1; d < 64; d <<= 1) s += __shfl_xor(s, d);
    if (lane == 0) {
        if (t0 == 0) tgt_ws[b] = s;
        else         tgt_ws[b] += s;
    }
}

// ---------------------------------------------------------------------------
// Scan over fused quad-products: 64 steps. One wave per chain.
// ---------------------------------------------------------------------------
__global__ __launch_bounds__(64, 1) void scan_q(
    const __hip_bfloat16* __restrict__ Q,    // [B*Tq][PST]
    float* __restrict__ p_ws, float* __restrict__ ls_ws,
    const float* __restrict__ tgt_ws, float* __restrict__ out,
    int t0q, int Tq, int Tqtot)
{
    __shared__ __align__(16) unsigned short p_arr[64];

    const int b    = blockIdx.x;
    const int lane = threadIdx.x;
    const int quad = lane >> 4;
    const int l16  = lane & 15;

    float pv[4] = {0.f, 0.f, 0.f, 0.f};
    float logscale = 0.f;
    if (t0q == 0) {
        p_arr[lane] = (lane == L_ - 1) ? (unsigned short)0x3F80 : (unsigned short)0;
    } else {
#pragma unroll
        for (int f = 0; f < 4; ++f) pv[f] = p_ws[b * 64 + f * 16 + l16];
        logscale = ls_ws[b];
        p_arr[quad * 16 + l16] = bf16bits(pv[quad]);
    }
    asm volatile("s_waitcnt lgkmcnt(0)" ::: "memory");

    int off[8];
#pragma unroll
    for (int f = 0; f < 4; ++f)
#pragma unroll
        for (int ks = 0; ks < 2; ++ks)
            off[f * 2 + ks] = (f * 16 + l16) * 8 + ks * 4 + quad;

    const u32x4* gp = (const u32x4*)Q + (size_t)b * Tq * (PST_ / 8);
    const u32x4_a* pa = (const u32x4_a*)p_arr;

    u32x4 s0[8], s1[8], s2[8], s3[8];
    auto fetch = [&](u32x4 (&st)[8], int tl) {
        const u32x4* g = gp + (size_t)tl * (PST_ / 8);
#pragma unroll
        for (int q = 0; q < 8; ++q) st[q] = g[off[q]];
    };
    fetch(s0, 0);
    if (1 < Tq) fetch(s1, 1);
    if (2 < Tq) fetch(s2, 2);
    if (3 < Tq) fetch(s3, 3);

    auto step = [&](u32x4 (&st)[8], int tl) {
        bf16x8 a0 = as_bf16x8(pa[quad]);
        bf16x8 a1 = as_bf16x8(pa[4 + quad]);
        const f32x4 z = {};
        f32x4 ae[4], ao[4];
#pragma unroll
        for (int f = 0; f < 4; ++f) {
            ae[f] = __builtin_amdgcn_mfma_f32_16x16x32_bf16(a0, as_bf16x8(st[f * 2 + 0]), z, 0, 0, 0);
            ao[f] = __builtin_amdgcn_mfma_f32_16x16x32_bf16(a1, as_bf16x8(st[f * 2 + 1]), z, 0, 0, 0);
        }
#pragma unroll
        for (int f = 0; f < 4; ++f) pv[f] = ae[f][0] + ao[f][0];

        if (((tl & 1) == 1) || (tl == Tq - 1)) {    // rescale every 2 fused steps
            float mx = fmaxf(fmaxf(pv[0], pv[1]), fmaxf(pv[2], pv[3]));
            DPP_STEP(mx, fmaxf, 0xB1);   // quad_perm xor1
            DPP_STEP(mx, fmaxf, 0x4E);   // quad_perm xor2
            DPP_STEP(mx, fmaxf, 0x124);  // row_ror:4
            DPP_STEP(mx, fmaxf, 0x128);  // row_ror:8
            const float inv = 1.f / mx;
            logscale += __logf(mx);
#pragma unroll
            for (int f = 0; f < 4; ++f) pv[f] *= inv;
        }
        p_arr[quad * 16 + l16] = bf16bits(pv[quad]);
        asm volatile("s_waitcnt lgkmcnt(0)" ::: "memory");
    };

    for (int tl = 0; tl < Tq; tl += 4) {
        step(s0, tl);
        if (tl + 4 < Tq) fetch(s0, tl + 4);
        if (tl + 1 < Tq) { step(s1, tl + 1); if (tl + 5 < Tq) fetch(s1, tl + 5); }
        if (tl + 2 < Tq) { step(s2, tl + 2); if (tl + 6 < Tq) fetch(s2, tl + 6); }
        if (tl + 3 < Tq) { step(s3, tl + 3); if (tl + 7 < Tq) fetch(s3, tl + 7); }
    }

    if (t0q + Tq == Tqtot) {
        float s = pv[0] + pv[1] + pv[2] + pv[3];
        DPP_STEP(s, addf, 0xB1);
        DPP_STEP(s, addf, 0x4E);
        DPP_STEP(s, addf, 0x124);
        DPP_STEP(s, addf, 0x128);
        if (lane == 0) out[b] = logscale + __logf(s) - tgt_ws[b];
    } else {
        if (quad == 0) {
#pragma unroll
            for (int f = 0; f < 4; ++f) p_ws[b * 64 + f * 16 + l16] = pv[f];
        }
        if (lane == 0) ls_ws[b] = logscale;
    }
}

// ---------------------------------------------------------------------------
extern "C" void kernel_launch(void* const* d_in, const int* in_sizes, int n_in,
                              void* d_out, int out_size, void* d_ws, size_t ws_size,
                              hipStream_t stream)
{
    (void)in_sizes; (void)n_in; (void)out_size;
    const float* x       = (const float*)d_in[0];
    const float* mask    = (const float*)d_in[1];
    const int*   target  = (const int*)d_in[2];
    const float* state_W = (const float*)d_in[3];
    const float* state_b = (const float*)d_in[4];
    const float* trans_W = (const float*)d_in[5];
    const float* trans_b = (const float*)d_in[6];
    float* out = (float*)d_out;

    char* ws = (char*)d_ws;
    size_t off = 0;
    auto alloc = [&](size_t bytes) -> void* {
        void* p = ws + off;
        off = (off + bytes + 255) & ~(size_t)255;
        return p;
    };

    __hip_bfloat16* Wt   = (__hip_bfloat16*)alloc((size_t)NG_ * K_ * 2);
    float*          bias = (float*)alloc((size_t)NG_ * 4);
    __hip_bfloat16* xb   = (__hip_bfloat16*)alloc((size_t)B_ * T_ * K_ * 2);
    float*          p_ws = (float*)alloc((size_t)B_ * 64 * 4);
    float*          ls   = (float*)alloc((size_t)B_ * 4);
    float*          tgte = (float*)alloc((size_t)B_ * 4);
    const size_t fixed = off;

    // P: Tc*B*PST*2  +  Q: (Tc/4)*B*PST*2
    int Tc = 256;
    while (Tc > 4 && fixed + (size_t)Tc * B_ * PST_ * 2 * 5 / 4 + 512 > ws_size) Tc >>= 1;
    __hip_bfloat16* P = (__hip_bfloat16*)alloc((size_t)Tc * B_ * PST_ * 2);
    __hip_bfloat16* Q = (__hip_bfloat16*)alloc((size_t)(Tc / 4) * B_ * PST_ * 2);
    int TcShift = 0;
    while ((1 << TcShift) < Tc) ++TcShift;

    prep_w<<<dim3(NG_ / 64), 256, 0, stream>>>(trans_W, trans_b, state_W, state_b, Wt, bias);
    prep_x<<<dim3(2048), 256, 0, stream>>>((const float4*)x, (ushort4*)xb, B_ * T_ * K_ / 4);
    zero_pad<<<dim3(2048), 256, 0, stream>>>((u32x4*)P, B_ * Tc);

    for (int t0 = 0; t0 < T_; t0 += Tc) {
        gemm_energy<<<dim3(NG_ / NT_, (B_ * Tc) / MT_), 256, 0, stream>>>(
            xb, Wt, bias, mask, P, t0, Tc, TcShift);
        prod_quad<<<dim3(B_ * (Tc / 4)), 256, 0, stream>>>(P, Q, Tc);
        tgt_kernel<<<dim3(B_), 64, 0, stream>>>(P, target, mask, tgte, t0, Tc);
        scan_q<<<dim3(B_), 64, 0, stream>>>(Q, p_ws, ls, tgte, out,
                                            t0 / 4, Tc / 4, T_ / 4);
    }
}

// Round 6
// 229.848 us; speedup vs baseline: 5.3812x; 1.0023x over previous
//
#include <hip/hip_runtime.h>
#include <hip/hip_bf16.h>

#define B_    64
#define T_    256
#define K_    256
#define L_    51
#define LL_   2601
#define RS_   64      // row stride inside one tile
#define NG_   3328    // GEMM N: 52*64 (j rows 0..51; row 51 zero)
#define PST_  4096    // tile stride per (b,t): 64 rows * 64 elems
#define MT_   128
#define NT_   128
#define TS_   72      // LDS transpose-buffer row stride (halfwords), 144B = 16B-aligned

typedef __bf16 bf16x8 __attribute__((ext_vector_type(8)));
typedef float  f32x4  __attribute__((ext_vector_type(4)));
typedef unsigned int u32x4 __attribute__((ext_vector_type(4)));
typedef u32x4 __attribute__((may_alias)) u32x4_a;
typedef unsigned long long ull;
typedef ull __attribute__((may_alias)) ull_a;

static __device__ __forceinline__ bf16x8 as_bf16x8(u32x4 u) {
    return __builtin_bit_cast(bf16x8, u);
}
static __device__ __forceinline__ unsigned short bf16bits(float x) {
    return __builtin_bit_cast(unsigned short, __float2bfloat16(x));
}
static __device__ __forceinline__ ull pack4(f32x4 a) {
    return (ull)bf16bits(a[0]) | ((ull)bf16bits(a[1]) << 16) |
           ((ull)bf16bits(a[2]) << 32) | ((ull)bf16bits(a[3]) << 48);
}
static __device__ __forceinline__ void gld_lds16(const void* g, void* l) {
    __builtin_amdgcn_global_load_lds(
        (const __attribute__((address_space(1))) unsigned int*)g,
        (__attribute__((address_space(3))) unsigned int*)l, 16, 0, 0);
}

// DPP reduction over the 16 l16-lanes (valid when values replicated per quad)
#define DPP_STEP(v, OP, CTRL)                                                   \
    {                                                                           \
        int _x = __builtin_bit_cast(int, v);                                    \
        float _o = __builtin_bit_cast(                                          \
            float, __builtin_amdgcn_update_dpp(_x, _x, CTRL, 0xF, 0xF, true));  \
        v = OP(v, _o);                                                          \
    }
static __device__ __forceinline__ float addf(float a, float b) { return a + b; }

// ---------------------------------------------------------------------------
// prep_w: Wt[n][k] = trans_W[k][i*51+j] + state_W[k][j],  n = j*64+i, bf16.
// ---------------------------------------------------------------------------
__global__ __launch_bounds__(256) void prep_w(
    const float* __restrict__ trans_W, const float* __restrict__ trans_b,
    const float* __restrict__ state_W, const float* __restrict__ state_b,
    __hip_bfloat16* __restrict__ Wt, float* __restrict__ bias)
{
    const int n  = blockIdx.x * 64 + (threadIdx.x >> 2);
    const int kq = (threadIdx.x & 3) * 64;
    const int j  = n >> 6;
    const int i  = n & 63;
    const bool valid = (i < L_) && (j < L_);
    const int o = i * L_ + j;

    __hip_bfloat16 tmp[64];
#pragma unroll
    for (int kk = 0; kk < 64; ++kk) {
        const int k = kq + kk;
        float w = valid ? (trans_W[(size_t)k * LL_ + o] + state_W[k * L_ + j]) : 0.f;
        tmp[kk] = __float2bfloat16(w);
    }
    u32x4* dst = (u32x4*)(Wt + (size_t)n * K_ + kq);
    const u32x4* src = (const u32x4*)tmp;
#pragma unroll
    for (int q = 0; q < 8; ++q) dst[q] = src[q];

    if ((threadIdx.x & 3) == 0)
        bias[n] = valid ? (trans_b[o] + state_b[j]) : 0.f;
}

__global__ void prep_x(const float4* __restrict__ x4, ushort4* __restrict__ xb4, int n4)
{
    for (int idx = blockIdx.x * blockDim.x + threadIdx.x; idx < n4;
         idx += gridDim.x * blockDim.x) {
        float4 v = x4[idx];
        ushort4 o;
        o.x = bf16bits(v.x); o.y = bf16bits(v.y);
        o.z = bf16bits(v.z); o.w = bf16bits(v.w);
        xb4[idx] = o;
    }
}

// zero pad region [NG_, PST_) of every (b,t) tile of P (rows j=52..63)
__global__ void zero_pad(u32x4* __restrict__ P16, int nBT)
{
    const int per = (PST_ - NG_) / 8;          // 96 chunks per tile
    const int tot = nBT * per;
    const u32x4 z = {};
    for (int idx = blockIdx.x * blockDim.x + threadIdx.x; idx < tot;
         idx += gridDim.x * blockDim.x) {
        const int m = idx / per;
        const int q = idx - m * per;
        P16[(size_t)m * (PST_ / 8) + (NG_ / 8) + q] = z;
    }
}

// ---------------------------------------------------------------------------
// GEMM + exp epilogue, LDS-staged, operand-swapped MFMA so each lane holds
// 4 consecutive n at fixed m -> packed 8B stores.
// P tile[j][i] = exp(energy[i][j]*mask); masked (m==0,t>0) tiles -> identity.
// ---------------------------------------------------------------------------
__global__ __launch_bounds__(256) void gemm_energy(
    const __hip_bfloat16* __restrict__ xb,   // [B*T][K]
    const __hip_bfloat16* __restrict__ Wt,   // [NG][K]
    const float* __restrict__ bias,          // [NG]
    const float* __restrict__ mask,          // [B][T]
    __hip_bfloat16* __restrict__ P,          // [B*Tc][PST]
    int t0, int Tc, int TcShift)
{
    __shared__ __align__(16) __hip_bfloat16 As[MT_ * 128];
    __shared__ __align__(16) __hip_bfloat16 Bs[NT_ * 128];

    const int tid  = threadIdx.x;
    const int lane = tid & 63;
    const int wv   = tid >> 6;
    const int quad = lane >> 4;
    const int l16  = lane & 15;
    const int m0 = blockIdx.y * MT_;
    const int n0 = blockIdx.x * NT_;
    const int mrow0 = (wv >> 1) * 64;
    const int ncol0 = (wv & 1) * 64;

    const int srow = wv * 4 + (lane >> 4);
    const int spos = lane & 15;

    f32x4 acc[4][4] = {};   // [nf][mf]

    for (int kp = 0; kp < 2; ++kp) {
        if (kp) __syncthreads();
#pragma unroll
        for (int it = 0; it < 8; ++it) {
            const int r  = it * 16 + srow;
            const int kc = spos ^ (r & 15);
            const int ma = m0 + r;
            const int rg = (ma >> TcShift) * T_ + t0 + (ma & (Tc - 1));
            gld_lds16((const char*)xb + (size_t)rg * 512 + kp * 256 + kc * 16,
                      (char*)As + it * 4096 + wv * 1024);
            gld_lds16((const char*)Wt + (size_t)(n0 + r) * 512 + kp * 256 + kc * 16,
                      (char*)Bs + it * 4096 + wv * 1024);
        }
        asm volatile("s_waitcnt vmcnt(0)" ::: "memory");
        __syncthreads();

        const u32x4_a* Av = (const u32x4_a*)As;
        const u32x4_a* Bv = (const u32x4_a*)Bs;
#pragma unroll
        for (int kk = 0; kk < 4; ++kk) {
            bf16x8 af[4], bfr[4];
#pragma unroll
            for (int f = 0; f < 4; ++f) {
                const int ra = mrow0 + f * 16 + l16;
                af[f]  = as_bf16x8(Av[ra * 16 + ((kk * 4 + quad) ^ (ra & 15))]);
                const int rb = ncol0 + f * 16 + l16;
                bfr[f] = as_bf16x8(Bv[rb * 16 + ((kk * 4 + quad) ^ (rb & 15))]);
            }
#pragma unroll
            for (int nf = 0; nf < 4; ++nf)
#pragma unroll
                for (int mf = 0; mf < 4; ++mf)
                    acc[nf][mf] = __builtin_amdgcn_mfma_f32_16x16x32_bf16(
                        bfr[nf], af[mf], acc[nf][mf], 0, 0, 0);
        }
    }

    // D[n-local = quad*4+r][m-local = l16]: lane holds 4 consecutive n, fixed m
    const int jcol = (n0 + ncol0) >> 6;     // wave-uniform tile row j
    const bool jok = jcol < L_;
#pragma unroll
    for (int mf = 0; mf < 4; ++mf) {
        const int m  = m0 + mrow0 + mf * 16 + l16;
        const int bb = m >> TcShift;
        const int tl = m & (Tc - 1);
        const int t  = t0 + tl;
        const float mval = mask[bb * T_ + t];
        const bool idm = (mval == 0.f) && (t != 0);
        __hip_bfloat16* prow = P + (size_t)m * PST_;
#pragma unroll
        for (int nf = 0; nf < 4; ++nf) {
            const int nbase = n0 + ncol0 + nf * 16 + quad * 4;
            const int ibase = nf * 16 + quad * 4;
            const f32x4 bv = *(const f32x4*)(bias + nbase);
            ull pk = 0;
#pragma unroll
            for (int r = 0; r < 4; ++r) {
                const int i = ibase + r;
                const bool ok = jok && (i < L_);
                float v;
                if (idm) v = (ok && i == jcol) ? 1.f : 0.f;
                else     v = ok ? __expf((acc[nf][mf][r] + bv[r]) * mval) : 0.f;
                pk |= (ull)bf16bits(v) << (16 * r);
            }
            *(ull_a*)(prow + nbase) = pk;
        }
    }
}

// ---------------------------------------------------------------------------
// prod_quad: Q = T4·T3·T2·T1, all-MFMA pair tree.
// Transposes via mfma(T_rows, Identity); every intermediate round-trips LDS
// through the natural 8B transposed-write (stride TS_, conflict-free).
// ---------------------------------------------------------------------------
__global__ __launch_bounds__(256) void prod_quad(
    const __hip_bfloat16* __restrict__ P,   // [B*Tc][PST]
    __hip_bfloat16* __restrict__ Q,         // [B*(Tc/4)][PST]
    int Tc)
{
    __shared__ u32x4 Sm[4][512];                            // T1..T4 swizzled, 32 KB
    __shared__ __align__(16) unsigned short T1t[64 * TS_];  // also reused as Mbuf
    __shared__ __align__(16) unsigned short T3t[64 * TS_];
    __shared__ __align__(16) unsigned short W2t[64 * TS_];  // W2^T rows
    __shared__ __align__(16) unsigned short W4b[64 * TS_];  // W4 rows

    const int tid  = threadIdx.x;
    const int wv   = tid >> 6;
    const int lane = tid & 63;
    const int quad = lane >> 4;
    const int l16  = lane & 15;
    const int bq = blockIdx.x;
    const int Tq = Tc >> 2;
    const int b  = bq / Tq;
    const int tq = bq - b * Tq;
    const __hip_bfloat16* tile0 = P + (size_t)(b * Tc + tq * 4) * PST_;

    // stage T1..T4 (chunk c of row r at slot r*8 + (c^(r&7)))
#pragma unroll
    for (int q = 0; q < 8; ++q) {
        const int idx  = q * 4 + wv;        // 0..31
        const int tile = idx >> 3;
        const int part = idx & 7;
        const int slot = part * 64 + lane;
        const int r    = slot >> 3;
        const int csrc = (slot & 7) ^ (r & 7);
        gld_lds16((const char*)(tile0 + (size_t)tile * PST_) + (r * 8 + csrc) * 16,
                  (char*)&Sm[tile][part * 64]);
    }

    // identity B-frags: even nf -> hit when quad==l16>>3; odd nf -> quad==2+(l16>>3)
    u32x4 idf[2];
    {
        const int e = l16 & 7;
        const unsigned int bits = (e & 1) ? 0x3F800000u : 0x3F80u;
#pragma unroll
        for (int par = 0; par < 2; ++par) {
            u32x4 v = {};
            if (quad == (l16 >> 3) + par * 2) v[e >> 1] = bits;
            idf[par] = v;
        }
    }

    const int ra = wv * 16 + l16;
    const f32x4 z = {};
    asm volatile("s_waitcnt vmcnt(0)" ::: "memory");
    __syncthreads();

    // Phase A: T1t = T1^T rows, T3t = T3^T rows (via identity MFMA)
#pragma unroll
    for (int tt = 0; tt < 2; ++tt) {
        const u32x4* S = Sm[tt * 2];
        bf16x8 a0 = as_bf16x8(S[ra * 8 + (quad ^ (ra & 7))]);
        bf16x8 a1 = as_bf16x8(S[ra * 8 + ((4 + quad) ^ (ra & 7))]);
        unsigned short* dst = tt ? T3t : T1t;
#pragma unroll
        for (int nf = 0; nf < 4; ++nf) {
            f32x4 d = __builtin_amdgcn_mfma_f32_16x16x32_bf16(
                (nf >> 1) ? a1 : a0, as_bf16x8(idf[nf & 1]), z, 0, 0, 0);
            *(ull_a*)(dst + (nf * 16 + l16) * TS_ + wv * 16 + quad * 4) = pack4(d);
        }
    }
    __syncthreads();

    // Phase B: W2 = T2·T1 (store W2^T rows); W4^T = T3^T·T4^T (store W4 rows)
    {
        bf16x8 a2[2], a3[2];
#pragma unroll
        for (int ks = 0; ks < 2; ++ks) {
            a2[ks] = as_bf16x8(Sm[1][ra * 8 + ((ks * 4 + quad) ^ (ra & 7))]);
            a3[ks] = as_bf16x8(*(const u32x4_a*)(T3t + ra * TS_ + ks * 32 + quad * 8));
        }
#pragma unroll
        for (int nf = 0; nf < 4; ++nf) {
            const int rb = nf * 16 + l16;
            f32x4 u = z, v = z;
#pragma unroll
            for (int ks = 0; ks < 2; ++ks) {
                bf16x8 bU = as_bf16x8(*(const u32x4_a*)(T1t + rb * TS_ + ks * 32 + quad * 8));
                bf16x8 bV = as_bf16x8(Sm[3][rb * 8 + ((ks * 4 + quad) ^ (rb & 7))]);
                u = __builtin_amdgcn_mfma_f32_16x16x32_bf16(a2[ks], bU, u, 0, 0, 0);
                v = __builtin_amdgcn_mfma_f32_16x16x32_bf16(a3[ks], bV, v, 0, 0, 0);
            }
            *(ull_a*)(W2t + rb * TS_ + wv * 16 + quad * 4) = pack4(u);
            *(ull_a*)(W4b + rb * TS_ + wv * 16 + quad * 4) = pack4(v);
        }
    }
    __syncthreads();

    // Phase C: M^T = W2^T·W4^... -> transposed-write gives M rows in Mbuf (=T1t)
    {
        bf16x8 aw[2];
#pragma unroll
        for (int ks = 0; ks < 2; ++ks)
            aw[ks] = as_bf16x8(*(const u32x4_a*)(W2t + ra * TS_ + ks * 32 + quad * 8));
#pragma unroll
        for (int nf = 0; nf < 4; ++nf) {
            const int rb = nf * 16 + l16;
            f32x4 d = z;
#pragma unroll
            for (int ks = 0; ks < 2; ++ks) {
                bf16x8 bw = as_bf16x8(*(const u32x4_a*)(W4b + rb * TS_ + ks * 32 + quad * 8));
                d = __builtin_amdgcn_mfma_f32_16x16x32_bf16(aw[ks], bw, d, 0, 0, 0);
            }
            *(ull_a*)(T1t + rb * TS_ + wv * 16 + quad * 4) = pack4(d);
        }
    }
    __syncthreads();

    // write Q tile: 16B stores
    u32x4* qout = (u32x4*)(Q + (size_t)bq * PST_);
#pragma unroll
    for (int c = tid; c < 512; c += 256) {
        const int row = c >> 3;
        const int pos = c & 7;
        qout[row * 8 + pos] = *(const u32x4_a*)(T1t + row * TS_ + pos * 8);
    }
}

// ---------------------------------------------------------------------------
// tgt: sum_t m_t ? log P[b,t][tgt_t*64 + prev] : 0
// ---------------------------------------------------------------------------
__global__ __launch_bounds__(64) void tgt_kernel(
    const __hip_bfloat16* __restrict__ P, const int* __restrict__ target,
    const float* __restrict__ mask, float* __restrict__ tgt_ws, int t0, int Tc)
{
    const int b = blockIdx.x, lane = threadIdx.x;
    float s = 0.f;
    for (int tl = lane; tl < Tc; tl += 64) {
        const int t = t0 + tl;
        const int j = target[b * T_ + t];
        const int i = (t == 0) ? (L_ - 1) : target[b * T_ + t - 1];
        const float m = (t == 0) ? 1.f : mask[b * T_ + t];
        if (m != 0.f) {
            const float pval = __bfloat162float(P[(size_t)(b * Tc + tl) * PST_ + j * RS_ + i]);
            s += __logf(pval);
        }
    }
#pragma unroll
    for (int d = 1; d < 64; d <<= 1) s += __shfl_xor(s, d);
    if (lane == 0) {
        if (t0 == 0) tgt_ws[b] = s;
        else         tgt_ws[b] += s;
    }
}

// ---------------------------------------------------------------------------
// Scan over fused quad-products: 64 steps. One wave per chain.
// ---------------------------------------------------------------------------
__global__ __launch_bounds__(64, 1) void scan_q(
    const __hip_bfloat16* __restrict__ Q,    // [B*Tq][PST]
    float* __restrict__ p_ws, float* __restrict__ ls_ws,
    const float* __restrict__ tgt_ws, float* __restrict__ out,
    int t0q, int Tq, int Tqtot)
{
    __shared__ __align__(16) unsigned short p_arr[64];

    const int b    = blockIdx.x;
    const int lane = threadIdx.x;
    const int quad = lane >> 4;
    const int l16  = lane & 15;

    float pv[4] = {0.f, 0.f, 0.f, 0.f};
    float logscale = 0.f;
    if (t0q == 0) {
        p_arr[lane] = (lane == L_ - 1) ? (unsigned short)0x3F80 : (unsigned short)0;
    } else {
#pragma unroll
        for (int f = 0; f < 4; ++f) pv[f] = p_ws[b * 64 + f * 16 + l16];
        logscale = ls_ws[b];
        p_arr[quad * 16 + l16] = bf16bits(pv[quad]);
    }
    asm volatile("s_waitcnt lgkmcnt(0)" ::: "memory");

    int off[8];
#pragma unroll
    for (int f = 0; f < 4; ++f)
#pragma unroll
        for (int ks = 0; ks < 2; ++ks)
            off[f * 2 + ks] = (f * 16 + l16) * 8 + ks * 4 + quad;

    const u32x4* gp = (const u32x4*)Q + (size_t)b * Tq * (PST_ / 8);
    const u32x4_a* pa = (const u32x4_a*)p_arr;

    u32x4 s0[8], s1[8], s2[8], s3[8];
    auto fetch = [&](u32x4 (&st)[8], int tl) {
        const u32x4* g = gp + (size_t)tl * (PST_ / 8);
#pragma unroll
        for (int q = 0; q < 8; ++q) st[q] = g[off[q]];
    };
    fetch(s0, 0);
    if (1 < Tq) fetch(s1, 1);
    if (2 < Tq) fetch(s2, 2);
    if (3 < Tq) fetch(s3, 3);

    auto step = [&](u32x4 (&st)[8], int tl) {
        bf16x8 a0 = as_bf16x8(pa[quad]);
        bf16x8 a1 = as_bf16x8(pa[4 + quad]);
        const f32x4 z = {};
        f32x4 ae[4], ao[4];
#pragma unroll
        for (int f = 0; f < 4; ++f) {
            ae[f] = __builtin_amdgcn_mfma_f32_16x16x32_bf16(a0, as_bf16x8(st[f * 2 + 0]), z, 0, 0, 0);
            ao[f] = __builtin_amdgcn_mfma_f32_16x16x32_bf16(a1, as_bf16x8(st[f * 2 + 1]), z, 0, 0, 0);
        }
#pragma unroll
        for (int f = 0; f < 4; ++f) pv[f] = ae[f][0] + ao[f][0];

        if (((tl & 1) == 1) || (tl == Tq - 1)) {    // rescale every 2 fused steps
            float mx = fmaxf(fmaxf(pv[0], pv[1]), fmaxf(pv[2], pv[3]));
            DPP_STEP(mx, fmaxf, 0xB1);
            DPP_STEP(mx, fmaxf, 0x4E);
            DPP_STEP(mx, fmaxf, 0x124);
            DPP_STEP(mx, fmaxf, 0x128);
            const float inv = 1.f / mx;
            logscale += __logf(mx);
#pragma unroll
            for (int f = 0; f < 4; ++f) pv[f] *= inv;
        }
        p_arr[quad * 16 + l16] = bf16bits(pv[quad]);
        asm volatile("s_waitcnt lgkmcnt(0)" ::: "memory");
    };

    for (int tl = 0; tl < Tq; tl += 4) {
        step(s0, tl);
        if (tl + 4 < Tq) fetch(s0, tl + 4);
        if (tl + 1 < Tq) { step(s1, tl + 1); if (tl + 5 < Tq) fetch(s1, tl + 5); }
        if (tl + 2 < Tq) { step(s2, tl + 2); if (tl + 6 < Tq) fetch(s2, tl + 6); }
        if (tl + 3 < Tq) { step(s3, tl + 3); if (tl + 7 < Tq) fetch(s3, tl + 7); }
    }

    if (t0q + Tq == Tqtot) {
        float s = pv[0] + pv[1] + pv[2] + pv[3];
        DPP_STEP(s, addf, 0xB1);
        DPP_STEP(s, addf, 0x4E);
        DPP_STEP(s, addf, 0x124);
        DPP_STEP(s, addf, 0x128);
        if (lane == 0) out[b] = logscale + __logf(s) - tgt_ws[b];
    } else {
        if (quad == 0) {
#pragma unroll
            for (int f = 0; f < 4; ++f) p_ws[b * 64 + f * 16 + l16] = pv[f];
        }
        if (lane == 0) ls_ws[b] = logscale;
    }
}

// ---------------------------------------------------------------------------
extern "C" void kernel_launch(void* const* d_in, const int* in_sizes, int n_in,
                              void* d_out, int out_size, void* d_ws, size_t ws_size,
                              hipStream_t stream)
{
    (void)in_sizes; (void)n_in; (void)out_size;
    const float* x       = (const float*)d_in[0];
    const float* mask    = (const float*)d_in[1];
    const int*   target  = (const int*)d_in[2];
    const float* state_W = (const float*)d_in[3];
    const float* state_b = (const float*)d_in[4];
    const float* trans_W = (const float*)d_in[5];
    const float* trans_b = (const float*)d_in[6];
    float* out = (float*)d_out;

    char* ws = (char*)d_ws;
    size_t off = 0;
    auto alloc = [&](size_t bytes) -> void* {
        void* p = ws + off;
        off = (off + bytes + 255) & ~(size_t)255;
        return p;
    };

    __hip_bfloat16* Wt   = (__hip_bfloat16*)alloc((size_t)NG_ * K_ * 2);
    float*          bias = (float*)alloc((size_t)NG_ * 4);
    __hip_bfloat16* xb   = (__hip_bfloat16*)alloc((size_t)B_ * T_ * K_ * 2);
    float*          p_ws = (float*)alloc((size_t)B_ * 64 * 4);
    float*          ls   = (float*)alloc((size_t)B_ * 4);
    float*          tgte = (float*)alloc((size_t)B_ * 4);
    const size_t fixed = off;

    // P: Tc*B*PST*2  +  Q: (Tc/4)*B*PST*2
    int Tc = 256;
    while (Tc > 4 && fixed + (size_t)Tc * B_ * PST_ * 2 * 5 / 4 + 512 > ws_size) Tc >>= 1;
    __hip_bfloat16* P = (__hip_bfloat16*)alloc((size_t)Tc * B_ * PST_ * 2);
    __hip_bfloat16* Q = (__hip_bfloat16*)alloc((size_t)(Tc / 4) * B_ * PST_ * 2);
    int TcShift = 0;
    while ((1 << TcShift) < Tc) ++TcShift;

    prep_w<<<dim3(NG_ / 64), 256, 0, stream>>>(trans_W, trans_b, state_W, state_b, Wt, bias);
    prep_x<<<dim3(2048), 256, 0, stream>>>((const float4*)x, (ushort4*)xb, B_ * T_ * K_ / 4);
    zero_pad<<<dim3(2048), 256, 0, stream>>>((u32x4*)P, B_ * Tc);

    for (int t0 = 0; t0 < T_; t0 += Tc) {
        gemm_energy<<<dim3(NG_ / NT_, (B_ * Tc) / MT_), 256, 0, stream>>>(
            xb, Wt, bias, mask, P, t0, Tc, TcShift);
        prod_quad<<<dim3(B_ * (Tc / 4)), 256, 0, stream>>>(P, Q, Tc);
        tgt_kernel<<<dim3(B_), 64, 0, stream>>>(P, target, mask, tgte, t0, Tc);
        scan_q<<<dim3(B_), 64, 0, stream>>>(Q, p_ws, ls, tgte, out,
                                            t0 / 4, Tc / 4, T_ / 4);
    }
}

// Round 7
// 213.908 us; speedup vs baseline: 5.7822x; 1.0745x over previous
//
#include <hip/hip_runtime.h>
#include <hip/hip_bf16.h>

#define B_    64
#define T_    256
#define K_    256
#define L_    51
#define LL_   2601
#define RS_   64      // row stride inside one tile
#define NG_   3328    // GEMM N: 52*64 (j rows 0..51; row 51 zero)
#define PST_  4096    // tile stride per (b,t): 64 rows * 64 elems
#define MT_   128
#define NT_   128
#define TS_   72      // prod_quad LDS transpose-buffer row stride (halfwords)
#define ES_   136     // gemm epilogue LDS row stride (halfwords), 272B = 16B-aligned

typedef __bf16 bf16x8 __attribute__((ext_vector_type(8)));
typedef float  f32x4  __attribute__((ext_vector_type(4)));
typedef unsigned int u32x4 __attribute__((ext_vector_type(4)));
typedef u32x4 __attribute__((may_alias)) u32x4_a;
typedef unsigned long long ull;
typedef ull __attribute__((may_alias)) ull_a;

static __device__ __forceinline__ bf16x8 as_bf16x8(u32x4 u) {
    return __builtin_bit_cast(bf16x8, u);
}
static __device__ __forceinline__ unsigned short bf16bits(float x) {
    return __builtin_bit_cast(unsigned short, __float2bfloat16(x));
}
static __device__ __forceinline__ ull pack4(f32x4 a) {
    return (ull)bf16bits(a[0]) | ((ull)bf16bits(a[1]) << 16) |
           ((ull)bf16bits(a[2]) << 32) | ((ull)bf16bits(a[3]) << 48);
}
static __device__ __forceinline__ void gld_lds16(const void* g, void* l) {
    __builtin_amdgcn_global_load_lds(
        (const __attribute__((address_space(1))) unsigned int*)g,
        (__attribute__((address_space(3))) unsigned int*)l, 16, 0, 0);
}

#define DPP_STEP(v, OP, CTRL)                                                   \
    {                                                                           \
        int _x = __builtin_bit_cast(int, v);                                    \
        float _o = __builtin_bit_cast(                                          \
            float, __builtin_amdgcn_update_dpp(_x, _x, CTRL, 0xF, 0xF, true));  \
        v = OP(v, _o);                                                          \
    }
static __device__ __forceinline__ float addf(float a, float b) { return a + b; }

// ---------------------------------------------------------------------------
// prep_all: blk [0,64)   -> Wt rows n=j*64+i for i=blk (LDS transpose) + bias
//           blk [64,1088)-> x fp32 -> bf16
//           blk [1088,2112) -> zero P tile pad rows [NG_,PST_)
// ---------------------------------------------------------------------------
__global__ __launch_bounds__(256) void prep_all(
    const float* __restrict__ trans_W, const float* __restrict__ trans_b,
    const float* __restrict__ state_W, const float* __restrict__ state_b,
    const float* __restrict__ x,
    __hip_bfloat16* __restrict__ Wt, float* __restrict__ bias,
    __hip_bfloat16* __restrict__ xb, __hip_bfloat16* __restrict__ P, int Tc)
{
    __shared__ __align__(16) __hip_bfloat16 Wl[52 * 258];
    const int blk = blockIdx.x, tid = threadIdx.x;

    if (blk < 64) {
        const int i = blk;
        if (i < L_) {
            const int jp = tid & 63, kk = tid >> 6;
            if (jp < 52) {
                for (int k = kk; k < K_; k += 4) {
                    float v = 0.f;
                    if (jp < L_) v = trans_W[(size_t)k * LL_ + i * L_ + jp] +
                                     state_W[k * L_ + jp];
                    Wl[jp * 258 + k] = __float2bfloat16(v);
                }
            }
            __syncthreads();
            for (int idx = tid; idx < 52 * 32; idx += 256) {
                const int j = idx >> 5, c = idx & 31;
                const unsigned int* row = (const unsigned int*)&Wl[j * 258];
                u32x4 v;
                v[0] = row[c * 4 + 0]; v[1] = row[c * 4 + 1];
                v[2] = row[c * 4 + 2]; v[3] = row[c * 4 + 3];
                *(u32x4*)(Wt + (size_t)((j << 6) + i) * K_ + c * 8) = v;
            }
        } else {
            const u32x4 z = {};
            for (int idx = tid; idx < 52 * 32; idx += 256) {
                const int j = idx >> 5, c = idx & 31;
                *(u32x4*)(Wt + (size_t)((j << 6) + i) * K_ + c * 8) = z;
            }
        }
        if (tid < 52) {
            const int j = tid;
            bias[(j << 6) + i] =
                (i < L_ && j < L_) ? trans_b[i * L_ + j] + state_b[j] : 0.f;
        }
    } else if (blk < 64 + 1024) {
        const int n4 = B_ * T_ * K_ / 4;
        const float4* x4 = (const float4*)x;
        ushort4* xb4 = (ushort4*)xb;
        for (int idx = (blk - 64) * 256 + tid; idx < n4; idx += 1024 * 256) {
            float4 v = x4[idx];
            ushort4 o;
            o.x = bf16bits(v.x); o.y = bf16bits(v.y);
            o.z = bf16bits(v.z); o.w = bf16bits(v.w);
            xb4[idx] = o;
        }
    } else {
        const int per = (PST_ - NG_) / 8;          // 96 chunks per tile
        const int tot = B_ * Tc * per;
        u32x4* P16 = (u32x4*)P;
        const u32x4 z = {};
        for (int idx = (blk - 1088) * 256 + tid; idx < tot; idx += 1024 * 256) {
            const int m = idx / per;
            const int q = idx - m * per;
            P16[(size_t)m * (PST_ / 8) + (NG_ / 8) + q] = z;
        }
    }
}

// ---------------------------------------------------------------------------
// GEMM + exp epilogue, LDS-staged both ways: MFMA with n-consecutive-in-lane
// D layout -> 8B packed LDS writes -> coalesced 16B global stores.
// P tile[j][i] = exp(energy[i][j]*mask); masked (m==0,t>0) tiles -> identity.
// ---------------------------------------------------------------------------
__global__ __launch_bounds__(256) void gemm_energy(
    const __hip_bfloat16* __restrict__ xb,   // [B*T][K]
    const __hip_bfloat16* __restrict__ Wt,   // [NG][K]
    const float* __restrict__ bias,          // [NG]
    const float* __restrict__ mask,          // [B][T]
    __hip_bfloat16* __restrict__ P,          // [B*Tc][PST]
    int t0, int Tc, int TcShift)
{
    __shared__ __align__(16) __hip_bfloat16 SH[2 * MT_ * 128];  // 64 KB union
    __hip_bfloat16* As = SH;
    __hip_bfloat16* Bs = SH + MT_ * 128;

    const int tid  = threadIdx.x;
    const int lane = tid & 63;
    const int wv   = tid >> 6;
    const int quad = lane >> 4;
    const int l16  = lane & 15;
    const int m0 = blockIdx.y * MT_;
    const int n0 = blockIdx.x * NT_;
    const int mrow0 = (wv >> 1) * 64;
    const int ncol0 = (wv & 1) * 64;

    const int srow = wv * 4 + (lane >> 4);
    const int spos = lane & 15;

    f32x4 acc[4][4] = {};   // [nf][mf]

    for (int kp = 0; kp < 2; ++kp) {
        if (kp) __syncthreads();
#pragma unroll
        for (int it = 0; it < 8; ++it) {
            const int r  = it * 16 + srow;
            const int kc = spos ^ (r & 15);
            const int ma = m0 + r;
            const int rg = (ma >> TcShift) * T_ + t0 + (ma & (Tc - 1));
            gld_lds16((const char*)xb + (size_t)rg * 512 + kp * 256 + kc * 16,
                      (char*)As + it * 4096 + wv * 1024);
            gld_lds16((const char*)Wt + (size_t)(n0 + r) * 512 + kp * 256 + kc * 16,
                      (char*)Bs + it * 4096 + wv * 1024);
        }
        asm volatile("s_waitcnt vmcnt(0)" ::: "memory");
        __syncthreads();

        const u32x4_a* Av = (const u32x4_a*)As;
        const u32x4_a* Bv = (const u32x4_a*)Bs;
#pragma unroll
        for (int kk = 0; kk < 4; ++kk) {
            bf16x8 af[4], bfr[4];
#pragma unroll
            for (int f = 0; f < 4; ++f) {
                const int ra = mrow0 + f * 16 + l16;
                af[f]  = as_bf16x8(Av[ra * 16 + ((kk * 4 + quad) ^ (ra & 15))]);
                const int rb = ncol0 + f * 16 + l16;
                bfr[f] = as_bf16x8(Bv[rb * 16 + ((kk * 4 + quad) ^ (rb & 15))]);
            }
#pragma unroll
            for (int nf = 0; nf < 4; ++nf)
#pragma unroll
                for (int mf = 0; mf < 4; ++mf)
                    acc[nf][mf] = __builtin_amdgcn_mfma_f32_16x16x32_bf16(
                        bfr[nf], af[mf], acc[nf][mf], 0, 0, 0);
        }
    }
    __syncthreads();   // done reading As/Bs; SH becomes the epilogue tile

    // epilogue: D[n-local = quad*4+r][m-local = l16] -> LDS [ml][nl] bf16
    unsigned short* E = (unsigned short*)SH;
    const int jcol = (n0 + ncol0) >> 6;     // wave-uniform tile row j
    const bool jok = jcol < L_;
#pragma unroll
    for (int mf = 0; mf < 4; ++mf) {
        const int ml = mrow0 + mf * 16 + l16;
        const int m  = m0 + ml;
        const int bb = m >> TcShift;
        const int tl = m & (Tc - 1);
        const int t  = t0 + tl;
        const float mval = mask[bb * T_ + t];
        const bool idm = (mval == 0.f) && (t != 0);
#pragma unroll
        for (int nf = 0; nf < 4; ++nf) {
            const int nl = ncol0 + nf * 16 + quad * 4;
            const f32x4 bv = *(const f32x4*)(bias + n0 + nl);
            ull pk = 0;
#pragma unroll
            for (int r = 0; r < 4; ++r) {
                const int i = (nl + r) & 63;
                const bool ok = jok && (i < L_);
                float v;
                if (idm) v = (ok && i == jcol) ? 1.f : 0.f;
                else     v = ok ? __expf((acc[nf][mf][r] + bv[r]) * mval) : 0.f;
                pk |= (ull)bf16bits(v) << (16 * r);
            }
            *(ull_a*)(E + ml * ES_ + nl) = pk;
        }
    }
    __syncthreads();

    // coalesced store: 16 lanes cover one row's 256B contiguous
#pragma unroll
    for (int it2 = 0; it2 < 8; ++it2) {
        const int idx = it2 * 256 + tid;
        const int ml = idx >> 4, c = idx & 15;
        const u32x4 v = *(const u32x4_a*)(E + ml * ES_ + c * 8);
        *(u32x4*)(P + (size_t)(m0 + ml) * PST_ + n0 + c * 8) = v;
    }
}

// ---------------------------------------------------------------------------
// prod_quad: Q = T4·T3·T2·T1, all-MFMA pair tree (unchanged from round 6).
// ---------------------------------------------------------------------------
__global__ __launch_bounds__(256) void prod_quad(
    const __hip_bfloat16* __restrict__ P,   // [B*Tc][PST]
    __hip_bfloat16* __restrict__ Q,         // [B*(Tc/4)][PST]
    int Tc)
{
    __shared__ u32x4 Sm[4][512];
    __shared__ __align__(16) unsigned short T1t[64 * TS_];
    __shared__ __align__(16) unsigned short T3t[64 * TS_];
    __shared__ __align__(16) unsigned short W2t[64 * TS_];
    __shared__ __align__(16) unsigned short W4b[64 * TS_];

    const int tid  = threadIdx.x;
    const int wv   = tid >> 6;
    const int lane = tid & 63;
    const int quad = lane >> 4;
    const int l16  = lane & 15;
    const int bq = blockIdx.x;
    const int Tq = Tc >> 2;
    const int b  = bq / Tq;
    const int tq = bq - b * Tq;
    const __hip_bfloat16* tile0 = P + (size_t)(b * Tc + tq * 4) * PST_;

#pragma unroll
    for (int q = 0; q < 8; ++q) {
        const int idx  = q * 4 + wv;
        const int tile = idx >> 3;
        const int part = idx & 7;
        const int slot = part * 64 + lane;
        const int r    = slot >> 3;
        const int csrc = (slot & 7) ^ (r & 7);
        gld_lds16((const char*)(tile0 + (size_t)tile * PST_) + (r * 8 + csrc) * 16,
                  (char*)&Sm[tile][part * 64]);
    }

    u32x4 idf[2];
    {
        const int e = l16 & 7;
        const unsigned int bits = (e & 1) ? 0x3F800000u : 0x3F80u;
#pragma unroll
        for (int par = 0; par < 2; ++par) {
            u32x4 v = {};
            if (quad == (l16 >> 3) + par * 2) v[e >> 1] = bits;
            idf[par] = v;
        }
    }

    const int ra = wv * 16 + l16;
    const f32x4 z = {};
    asm volatile("s_waitcnt vmcnt(0)" ::: "memory");
    __syncthreads();

#pragma unroll
    for (int tt = 0; tt < 2; ++tt) {
        const u32x4* S = Sm[tt * 2];
        bf16x8 a0 = as_bf16x8(S[ra * 8 + (quad ^ (ra & 7))]);
        bf16x8 a1 = as_bf16x8(S[ra * 8 + ((4 + quad) ^ (ra & 7))]);
        unsigned short* dst = tt ? T3t : T1t;
#pragma unroll
        for (int nf = 0; nf < 4; ++nf) {
            f32x4 d = __builtin_amdgcn_mfma_f32_16x16x32_bf16(
                (nf >> 1) ? a1 : a0, as_bf16x8(idf[nf & 1]), z, 0, 0, 0);
            *(ull_a*)(dst + (nf * 16 + l16) * TS_ + wv * 16 + quad * 4) = pack4(d);
        }
    }
    __syncthreads();

    {
        bf16x8 a2[2], a3[2];
#pragma unroll
        for (int ks = 0; ks < 2; ++ks) {
            a2[ks] = as_bf16x8(Sm[1][ra * 8 + ((ks * 4 + quad) ^ (ra & 7))]);
            a3[ks] = as_bf16x8(*(const u32x4_a*)(T3t + ra * TS_ + ks * 32 + quad * 8));
        }
#pragma unroll
        for (int nf = 0; nf < 4; ++nf) {
            const int rb = nf * 16 + l16;
            f32x4 u = z, v = z;
#pragma unroll
            for (int ks = 0; ks < 2; ++ks) {
                bf16x8 bU = as_bf16x8(*(const u32x4_a*)(T1t + rb * TS_ + ks * 32 + quad * 8));
                bf16x8 bV = as_bf16x8(Sm[3][rb * 8 + ((ks * 4 + quad) ^ (rb & 7))]);
                u = __builtin_amdgcn_mfma_f32_16x16x32_bf16(a2[ks], bU, u, 0, 0, 0);
                v = __builtin_amdgcn_mfma_f32_16x16x32_bf16(a3[ks], bV, v, 0, 0, 0);
            }
            *(ull_a*)(W2t + rb * TS_ + wv * 16 + quad * 4) = pack4(u);
            *(ull_a*)(W4b + rb * TS_ + wv * 16 + quad * 4) = pack4(v);
        }
    }
    __syncthreads();

    {
        bf16x8 aw[2];
#pragma unroll
        for (int ks = 0; ks < 2; ++ks)
            aw[ks] = as_bf16x8(*(const u32x4_a*)(W2t + ra * TS_ + ks * 32 + quad * 8));
#pragma unroll
        for (int nf = 0; nf < 4; ++nf) {
            const int rb = nf * 16 + l16;
            f32x4 d = z;
#pragma unroll
            for (int ks = 0; ks < 2; ++ks) {
                bf16x8 bw = as_bf16x8(*(const u32x4_a*)(W4b + rb * TS_ + ks * 32 + quad * 8));
                d = __builtin_amdgcn_mfma_f32_16x16x32_bf16(aw[ks], bw, d, 0, 0, 0);
            }
            *(ull_a*)(T1t + rb * TS_ + wv * 16 + quad * 4) = pack4(d);
        }
    }
    __syncthreads();

    u32x4* qout = (u32x4*)(Q + (size_t)bq * PST_);
#pragma unroll
    for (int c = tid; c < 512; c += 256) {
        const int row = c >> 3;
        const int pos = c & 7;
        qout[row * 8 + pos] = *(const u32x4_a*)(T1t + row * TS_ + pos * 8);
    }
}

// ---------------------------------------------------------------------------
// scan_q: wave 0 = serial scan over quad-products (64 steps);
//         wave 1 = target-path gather (concurrent, off the critical path).
// ---------------------------------------------------------------------------
__global__ __launch_bounds__(128, 1) void scan_q(
    const __hip_bfloat16* __restrict__ Q,    // [B*Tq][PST]
    const __hip_bfloat16* __restrict__ P,    // [B*Tc][PST]
    const int* __restrict__ target, const float* __restrict__ mask,
    float* __restrict__ p_ws, float* __restrict__ ls_ws,
    float* __restrict__ tgt_ws, float* __restrict__ out,
    int t0q, int Tq, int Tqtot)
{
    __shared__ __align__(16) unsigned short p_arr[64];
    __shared__ float tgt_sh;

    const int b    = blockIdx.x;
    const int tid  = threadIdx.x;
    const int wv   = tid >> 6;
    const int lane = tid & 63;
    const int quad = lane >> 4;
    const int l16  = lane & 15;
    const int t0 = t0q << 2, Tc = Tq << 2;

    float pv[4] = {0.f, 0.f, 0.f, 0.f};
    float logscale = 0.f;

    if (wv == 0) {
        if (t0q == 0) {
            p_arr[lane] = (lane == L_ - 1) ? (unsigned short)0x3F80 : (unsigned short)0;
        } else {
#pragma unroll
            for (int f = 0; f < 4; ++f) pv[f] = p_ws[b * 64 + f * 16 + l16];
            logscale = ls_ws[b];
            p_arr[quad * 16 + l16] = bf16bits(pv[quad]);
        }
        asm volatile("s_waitcnt lgkmcnt(0)" ::: "memory");

        int off[8];
#pragma unroll
        for (int f = 0; f < 4; ++f)
#pragma unroll
            for (int ks = 0; ks < 2; ++ks)
                off[f * 2 + ks] = (f * 16 + l16) * 8 + ks * 4 + quad;

        const u32x4* gp = (const u32x4*)Q + (size_t)b * Tq * (PST_ / 8);
        const u32x4_a* pa = (const u32x4_a*)p_arr;

        u32x4 s0[8], s1[8], s2[8], s3[8];
        auto fetch = [&](u32x4 (&st)[8], int tl) {
            const u32x4* g = gp + (size_t)tl * (PST_ / 8);
#pragma unroll
            for (int q = 0; q < 8; ++q) st[q] = g[off[q]];
        };
        fetch(s0, 0);
        if (1 < Tq) fetch(s1, 1);
        if (2 < Tq) fetch(s2, 2);
        if (3 < Tq) fetch(s3, 3);

        auto step = [&](u32x4 (&st)[8], int tl) {
            bf16x8 a0 = as_bf16x8(pa[quad]);
            bf16x8 a1 = as_bf16x8(pa[4 + quad]);
            const f32x4 z = {};
            f32x4 ae[4], ao[4];
#pragma unroll
            for (int f = 0; f < 4; ++f) {
                ae[f] = __builtin_amdgcn_mfma_f32_16x16x32_bf16(a0, as_bf16x8(st[f * 2 + 0]), z, 0, 0, 0);
                ao[f] = __builtin_amdgcn_mfma_f32_16x16x32_bf16(a1, as_bf16x8(st[f * 2 + 1]), z, 0, 0, 0);
            }
#pragma unroll
            for (int f = 0; f < 4; ++f) pv[f] = ae[f][0] + ao[f][0];

            if (((tl & 1) == 1) || (tl == Tq - 1)) {
                float mx = fmaxf(fmaxf(pv[0], pv[1]), fmaxf(pv[2], pv[3]));
                DPP_STEP(mx, fmaxf, 0xB1);
                DPP_STEP(mx, fmaxf, 0x4E);
                DPP_STEP(mx, fmaxf, 0x124);
                DPP_STEP(mx, fmaxf, 0x128);
                const float inv = 1.f / mx;
                logscale += __logf(mx);
#pragma unroll
                for (int f = 0; f < 4; ++f) pv[f] *= inv;
            }
            p_arr[quad * 16 + l16] = bf16bits(pv[quad]);
            asm volatile("s_waitcnt lgkmcnt(0)" ::: "memory");
        };

        for (int tl = 0; tl < Tq; tl += 4) {
            step(s0, tl);
            if (tl + 4 < Tq) fetch(s0, tl + 4);
            if (tl + 1 < Tq) { step(s1, tl + 1); if (tl + 5 < Tq) fetch(s1, tl + 5); }
            if (tl + 2 < Tq) { step(s2, tl + 2); if (tl + 6 < Tq) fetch(s2, tl + 6); }
            if (tl + 3 < Tq) { step(s3, tl + 3); if (tl + 7 < Tq) fetch(s3, tl + 7); }
        }
    } else {
        // target-path gather
        float s = 0.f;
        for (int tl = lane; tl < Tc; tl += 64) {
            const int t = t0 + tl;
            const int j = target[b * T_ + t];
            const int i = (t == 0) ? (L_ - 1) : target[b * T_ + t - 1];
            const float m = (t == 0) ? 1.f : mask[b * T_ + t];
            if (m != 0.f) {
                const float pval =
                    __bfloat162float(P[(size_t)(b * Tc + tl) * PST_ + j * RS_ + i]);
                s += __logf(pval);
            }
        }
#pragma unroll
        for (int d = 1; d < 64; d <<= 1) s += __shfl_xor(s, d);
        if (lane == 0) {
            const float tot = (t0 == 0) ? s : tgt_ws[b] + s;
            tgt_ws[b] = tot;
            tgt_sh = tot;
        }
    }
    __syncthreads();

    if (wv == 0) {
        if (t0q + Tq == Tqtot) {
            float s = pv[0] + pv[1] + pv[2] + pv[3];
            DPP_STEP(s, addf, 0xB1);
            DPP_STEP(s, addf, 0x4E);
            DPP_STEP(s, addf, 0x124);
            DPP_STEP(s, addf, 0x128);
            if (lane == 0) out[b] = logscale + __logf(s) - tgt_sh;
        } else {
            if (quad == 0) {
#pragma unroll
                for (int f = 0; f < 4; ++f) p_ws[b * 64 + f * 16 + l16] = pv[f];
            }
            if (lane == 0) ls_ws[b] = logscale;
        }
    }
}

// ---------------------------------------------------------------------------
extern "C" void kernel_launch(void* const* d_in, const int* in_sizes, int n_in,
                              void* d_out, int out_size, void* d_ws, size_t ws_size,
                              hipStream_t stream)
{
    (void)in_sizes; (void)n_in; (void)out_size;
    const float* x       = (const float*)d_in[0];
    const float* mask    = (const float*)d_in[1];
    const int*   target  = (const int*)d_in[2];
    const float* state_W = (const float*)d_in[3];
    const float* state_b = (const float*)d_in[4];
    const float* trans_W = (const float*)d_in[5];
    const float* trans_b = (const float*)d_in[6];
    float* out = (float*)d_out;

    char* ws = (char*)d_ws;
    size_t off = 0;
    auto alloc = [&](size_t bytes) -> void* {
        void* p = ws + off;
        off = (off + bytes + 255) & ~(size_t)255;
        return p;
    };

    __hip_bfloat16* Wt   = (__hip_bfloat16*)alloc((size_t)NG_ * K_ * 2);
    float*          bias = (float*)alloc((size_t)NG_ * 4);
    __hip_bfloat16* xb   = (__hip_bfloat16*)alloc((size_t)B_ * T_ * K_ * 2);
    float*          p_ws = (float*)alloc((size_t)B_ * 64 * 4);
    float*          ls   = (float*)alloc((size_t)B_ * 4);
    float*          tgte = (float*)alloc((size_t)B_ * 4);
    const size_t fixed = off;

    int Tc = 256;
    while (Tc > 4 && fixed + (size_t)Tc * B_ * PST_ * 2 * 5 / 4 + 512 > ws_size) Tc >>= 1;
    __hip_bfloat16* P = (__hip_bfloat16*)alloc((size_t)Tc * B_ * PST_ * 2);
    __hip_bfloat16* Q = (__hip_bfloat16*)alloc((size_t)(Tc / 4) * B_ * PST_ * 2);
    int TcShift = 0;
    while ((1 << TcShift) < Tc) ++TcShift;

    prep_all<<<dim3(2112), 256, 0, stream>>>(
        trans_W, trans_b, state_W, state_b, x, Wt, bias, xb, P, Tc);

    for (int t0 = 0; t0 < T_; t0 += Tc) {
        gemm_energy<<<dim3(NG_ / NT_, (B_ * Tc) / MT_), 256, 0, stream>>>(
            xb, Wt, bias, mask, P, t0, Tc, TcShift);
        prod_quad<<<dim3(B_ * (Tc / 4)), 256, 0, stream>>>(P, Q, Tc);
        scan_q<<<dim3(B_), 128, 0, stream>>>(Q, P, target, mask, p_ws, ls, tgte, out,
                                             t0 / 4, Tc / 4, T_ / 4);
    }
}